// Round 4
// baseline (877.879 us; speedup 1.0000x reference)
//
#include <hip/hip_runtime.h>
#include <math.h>

#define B_   32
#define P_   196
#define F_   2048
#define E_   512
#define H_   512
#define V_   10000
#define T_   20
#define GSZ  8            // blocks per batch-element group
#define NBLK (B_ * GSZ)   // 256 persistent blocks = 1 per CU (LDS-limited)

typedef unsigned short ushort_t;
typedef ushort_t u16x8 __attribute__((ext_vector_type(8)));
typedef ushort_t u16x2 __attribute__((ext_vector_type(2)));
typedef short    bf16x8 __attribute__((ext_vector_type(8)));
typedef float    f32x4  __attribute__((ext_vector_type(4)));

__device__ __forceinline__ ushort_t bf_rne(float x) {
    union { float f; unsigned u; } v; v.f = x;
    unsigned r = v.u + 0x7FFFu + ((v.u >> 16) & 1u);
    return (ushort_t)(r >> 16);
}
__device__ __forceinline__ float b2f(ushort_t u) {
    union { unsigned u; float f; } v; v.u = ((unsigned)u) << 16;
    return v.f;
}

// async global->LDS, 16B per lane. LDS dest is wave-uniform base + lane*16.
__device__ __forceinline__ void gl_lds16(const ushort_t* g, ushort_t* l) {
    __builtin_amdgcn_global_load_lds(
        (const __attribute__((address_space(1))) void*)g,
        (__attribute__((address_space(3))) void*)l, 16, 0, 0);
}

// Column permutation: g-col j -> P(j) = s_own*256 + ri*32 + gi*8 + e.
// chunk=j>>3, gi=chunk>>6 (gate), r=chunk&63, owner=r&7, ri=r>>3, e=j&7.
// Gate stride 512 = 64 chunks -> all 4 gates of one hidden unit share owner.
__device__ __forceinline__ int permc(int chunk) {   // chunk in [0,256) -> new chunk
    int gi = chunk >> 6, r = chunk & 63;
    return (r & 7) * 32 + (r >> 3) * 4 + gi;
}

// ---------------------------------------------------------------------------
// One-time conversion mega-kernel (1 node): bf16 converts / extracts /
// transposes / caption-gather / g-col permutations. 13125 blocks x 256 thr.
// ---------------------------------------------------------------------------
__global__ __launch_bounds__(256)
void cvt_all_kernel(const float* __restrict__ feat, const float* __restrict__ enc_W,
                    const float* __restrict__ fc_W, const float* __restrict__ dec_W,
                    const float* __restrict__ W_ih, const float* __restrict__ W_hh,
                    const float* __restrict__ emb, const int* __restrict__ captions,
                    const float* __restrict__ b_ih, const float* __restrict__ b_hh,
                    ushort_t* __restrict__ featB, ushort_t* __restrict__ encWB,
                    ushort_t* __restrict__ fcWB, ushort_t* __restrict__ decWB,
                    ushort_t* __restrict__ WihCB, ushort_t* __restrict__ WihEB,
                    ushort_t* __restrict__ WhhT, ushort_t* __restrict__ XB,
                    float* __restrict__ bsum, float* __restrict__ zbuf)
{
    const int blk = blockIdx.x, tid = threadIdx.x;
    if (blk < 6272) {                       // featB flat
        size_t i = (size_t)blk * 2048 + tid * 8;
        float4 a = *(const float4*)&feat[i], b = *(const float4*)&feat[i + 4];
        u16x8 o; o[0]=bf_rne(a.x); o[1]=bf_rne(a.y); o[2]=bf_rne(a.z); o[3]=bf_rne(a.w);
        o[4]=bf_rne(b.x); o[5]=bf_rne(b.y); o[6]=bf_rne(b.z); o[7]=bf_rne(b.w);
        *(u16x8*)&featB[i] = o;
    } else if (blk < 6784) {                // encWB
        size_t i = (size_t)(blk - 6272) * 2048 + tid * 8;
        float4 a = *(const float4*)&enc_W[i], b = *(const float4*)&enc_W[i + 4];
        u16x8 o; o[0]=bf_rne(a.x); o[1]=bf_rne(a.y); o[2]=bf_rne(a.z); o[3]=bf_rne(a.w);
        o[4]=bf_rne(b.x); o[5]=bf_rne(b.y); o[6]=bf_rne(b.z); o[7]=bf_rne(b.w);
        *(u16x8*)&encWB[i] = o;
    } else if (blk < 9284) {                // fcWB
        size_t i = (size_t)(blk - 6784) * 2048 + tid * 8;
        float4 a = *(const float4*)&fc_W[i], b = *(const float4*)&fc_W[i + 4];
        u16x8 o; o[0]=bf_rne(a.x); o[1]=bf_rne(a.y); o[2]=bf_rne(a.z); o[3]=bf_rne(a.w);
        o[4]=bf_rne(b.x); o[5]=bf_rne(b.y); o[6]=bf_rne(b.z); o[7]=bf_rne(b.w);
        *(u16x8*)&fcWB[i] = o;
    } else if (blk < 9412) {                // decWB
        size_t i = (size_t)(blk - 9284) * 2048 + tid * 8;
        float4 a = *(const float4*)&dec_W[i], b = *(const float4*)&dec_W[i + 4];
        u16x8 o; o[0]=bf_rne(a.x); o[1]=bf_rne(a.y); o[2]=bf_rne(a.z); o[3]=bf_rne(a.w);
        o[4]=bf_rne(b.x); o[5]=bf_rne(b.y); o[6]=bf_rne(b.z); o[7]=bf_rne(b.w);
        *(u16x8*)&decWB[i] = o;
    } else if (blk < 11460) {               // WihCB[P(j)] = bf16(W_ih[j, 512:2560])
        int j = blk - 9412, f = tid * 8;
        int Pj = permc(j >> 3) * 8 + (j & 7);
        const float* s = &W_ih[(size_t)j * 2560 + 512 + f];
        float4 a = *(const float4*)&s[0], b = *(const float4*)&s[4];
        u16x8 o; o[0]=bf_rne(a.x); o[1]=bf_rne(a.y); o[2]=bf_rne(a.z); o[3]=bf_rne(a.w);
        o[4]=bf_rne(b.x); o[5]=bf_rne(b.y); o[6]=bf_rne(b.z); o[7]=bf_rne(b.w);
        *(u16x8*)&WihCB[(size_t)Pj * 2048 + f] = o;
    } else if (blk < 11972) {               // WihEB[P(j)] = bf16(W_ih[j, 0:512])
        size_t idx = (size_t)(blk - 11460) * 2048 + tid * 8;
        int j = (int)(idx >> 9), f = (int)(idx & 511);
        int Pj = permc(j >> 3) * 8 + (j & 7);
        const float* s = &W_ih[(size_t)j * 2560 + f];
        float4 a = *(const float4*)&s[0], b = *(const float4*)&s[4];
        u16x8 o; o[0]=bf_rne(a.x); o[1]=bf_rne(a.y); o[2]=bf_rne(a.z); o[3]=bf_rne(a.w);
        o[4]=bf_rne(b.x); o[5]=bf_rne(b.y); o[6]=bf_rne(b.z); o[7]=bf_rne(b.w);
        *(u16x8*)&WihEB[(size_t)Pj * 512 + f] = o;
    } else if (blk < 12484) {               // WhhT[k][P(j)] = bf16(W_hh[j][k])
        int k = blk - 11972, j0 = tid * 8;
        int nc = permc(tid);
        u16x8 o;
#pragma unroll
        for (int q = 0; q < 8; q++) o[q] = bf_rne(W_hh[(size_t)(j0 + q) * 512 + k]);
        *(u16x8*)&WhhT[(size_t)k * 2048 + nc * 8] = o;
    } else if (blk < 13124) {               // XB[m] = bf16(emb[captions]), m = t*32+b
        int m = blk - 12484;
        int tt = m >> 5, b = m & 31;
        int cap = captions[b * T_ + tt];
        int i = tid * 2;
        u16x2 o;
        o[0] = bf_rne(emb[(size_t)cap * 512 + i]);
        o[1] = bf_rne(emb[(size_t)cap * 512 + i + 1]);
        *(u16x2*)&XB[(size_t)m * 512 + i] = o;
    } else {                                // bsum (permuted) + zbuf
        int nc = permc(tid);
        int j0 = tid * 8;
#pragma unroll
        for (int q = 0; q < 8; q++) {
            bsum[nc * 8 + q] = b_ih[j0 + q] + b_hh[j0 + q];
            zbuf[j0 + q] = 0.f;
        }
    }
}

// ---------------------------------------------------------------------------
// bf16 MFMA GEMM: C[m,n] = A[m,:].B[n,:] + bias, A/B bf16 K-major.
// 128x128 tile, 4 waves, 4x4 of 16x16x32 MFMA per wave.
// Staging via global_load_lds width=16 (linear LDS layout, wave-uniform base).
// mode 0: bf16 store, bias[n].  mode 1: f32 store, crow=(m&31)*20+(m>>5).
// mode 2: f32 store plain.      mode 3: bf16 store, ROW bias[m].
// ---------------------------------------------------------------------------
__global__ __launch_bounds__(256)
void mfma_gemm_kernel(const ushort_t* __restrict__ A, const ushort_t* __restrict__ B,
                      const float* __restrict__ bias, ushort_t* __restrict__ Cb,
                      float* __restrict__ Cf, int K, int N, int mode)
{
    __shared__ ushort_t As[128][32];
    __shared__ ushort_t Bs[128][32];
    const int tid = threadIdx.x;
    const int m0 = blockIdx.x * 128, n0 = blockIdx.y * 128;
    const int wave = tid >> 6, lane = tid & 63;
    const int wm = (wave & 1) * 64, wn = (wave >> 1) * 64;
    const int lm = lane & 15, lk = (lane >> 4) * 8;

    f32x4 acc[4][4];
#pragma unroll
    for (int mt = 0; mt < 4; mt++)
#pragma unroll
        for (int nt = 0; nt < 4; nt++)
#pragma unroll
            for (int r = 0; r < 4; r++) acc[mt][nt][r] = 0.f;

    for (int k0 = 0; k0 < K; k0 += 32) {
#pragma unroll
        for (int i = 0; i < 2; i++) {
            int gi  = tid + i * 256;
            int row = gi >> 2;
            int gr  = (gi & 3) * 8;
            // LDS offset for this lane is gi*16B = wave-uniform base + lane*16B
            ushort_t* lbA = &As[0][0] + (size_t)(wave * 64 + i * 256) * 8;
            ushort_t* lbB = &Bs[0][0] + (size_t)(wave * 64 + i * 256) * 8;
            gl_lds16(&A[(size_t)(m0 + row) * K + k0 + gr], lbA);
            int brow = n0 + row; if (brow >= N) brow = N - 1;
            gl_lds16(&B[(size_t)brow * K + k0 + gr], lbB);
        }
        __syncthreads();
        bf16x8 af[4], bv[4];
#pragma unroll
        for (int mt = 0; mt < 4; mt++)
            af[mt] = *(const bf16x8*)&As[wm + mt * 16 + lm][lk];
#pragma unroll
        for (int nt = 0; nt < 4; nt++)
            bv[nt] = *(const bf16x8*)&Bs[wn + nt * 16 + lm][lk];
#pragma unroll
        for (int mt = 0; mt < 4; mt++)
#pragma unroll
            for (int nt = 0; nt < 4; nt++)
                acc[mt][nt] = __builtin_amdgcn_mfma_f32_16x16x32_bf16(
                    af[mt], bv[nt], acc[mt][nt], 0, 0, 0);
        __syncthreads();
    }

    const int rb = (lane >> 4) * 4;
#pragma unroll
    for (int nt = 0; nt < 4; nt++) {
        int n = n0 + wn + nt * 16 + lm;
        int nc = n < N ? n : N - 1;
        float bz = (mode == 3) ? 0.f : bias[nc];
#pragma unroll
        for (int mt = 0; mt < 4; mt++) {
            int mbase = m0 + wm + mt * 16 + rb;
#pragma unroll
            for (int r = 0; r < 4; r++) {
                int m = mbase + r;
                float v = acc[mt][nt][r] + ((mode == 3) ? bias[m] : bz);
                if (mode == 0 || mode == 3) {
                    Cb[(size_t)m * N + n] = bf_rne(v);
                } else if (n < N) {
                    int crow = (mode == 1) ? ((m & 31) * 20 + (m >> 5)) : m;
                    Cf[(size_t)crow * N + n] = v;
                }
            }
        }
    }
}

// Relaxed-only poll: NO acquire -> no L2 invalidate, weights stay L2-hot.
// Cross-block payloads move via agent-scope relaxed atomic load/store.
__device__ __forceinline__ void wait_cnt(unsigned* p, unsigned target) {
    if (threadIdx.x == 0) {
        while (__hip_atomic_load(p, __ATOMIC_RELAXED, __HIP_MEMORY_SCOPE_AGENT) < target)
            __builtin_amdgcn_s_sleep(1);
    }
    __syncthreads();
}

// ---------------------------------------------------------------------------
// Persistent 20-step decoder. 256 blocks = 32 groups x 8. Block (b,s):
//  - owns 256 permuted g-cols: WhhT slice PINNED IN REGISTERS (64 x u16x8 =
//    256 VGPR/thread, loaded once), alpha.G slice (G in LDS, staged once),
//    local pointwise (c in regs).
//  - owns attention a-slice [s*64,s*64+64): encPT slice PINNED IN LDS
//    (25.6 KB, staged once) -> energies loop is pure LDS, no L2 latency.
// Per step: h-hop (relaxed poll + agent loads), dps (decW from L2),
// energies (LDS), publish epart, Whh.h (registers, overlaps e-hop),
// gather+softmax, alpha.G (LDS), pointwise, publish h.
// ---------------------------------------------------------------------------
__global__ __launch_bounds__(256, 1)
void persist_kernel(float* __restrict__ hbuf,           // [2][32][512]
                    ushort_t* __restrict__ hseqB,       // [21][32][512]
                    const ushort_t* __restrict__ encPT, // [512][6272] a-major
                    const ushort_t* __restrict__ decWB, // [512][512]
                    const float* __restrict__ dec_b,
                    const float* __restrict__ full_W,
                    const float* __restrict__ full_b,
                    const ushort_t* __restrict__ GB,    // [6272][2048] col-permuted
                    const ushort_t* __restrict__ WhhT,  // [512][2048] col-permuted
                    const float* __restrict__ xproj,    // [640][2048] col-permuted
                    float* __restrict__ epartG,         // [32][8][200]
                    unsigned* __restrict__ hcnt,        // [32][32]
                    unsigned* __restrict__ ecnt)        // [32][32]
{
    __shared__ ushort_t Gs[196][256];   // 100,352 B: this block's G col-slice
    __shared__ ushort_t ePs[64][200];   // 25,600 B: this block's encPT a-slice
    __shared__ float hsh[512];
    __shared__ float fws[512];
    __shared__ float dps64[64];
    __shared__ float es[200];
    __shared__ float al[200];
    __shared__ float sred[8][32][9];    // padded: conflict-free reduce scratch
    __shared__ float gsh[256];

    const int tid = threadIdx.x;
    const int b = blockIdx.x & 31;      // all 8 blocks of b -> same XCD
    const int s = blockIdx.x >> 5;
    unsigned* hcn = &hcnt[b * 32];
    unsigned* ecn = &ecnt[b * 32];
    float* epb = epartG + (size_t)b * 1600;

    // ---- one-time: stage this block's (contiguous, permuted) G slice
    {
        const int r0 = tid >> 5, c = (tid & 31) * 8;
        for (int i = 0; i < 25; i++) {
            int r = i * 8 + r0;
            if (r < 196)
                *(u16x8*)&Gs[r][c] =
                    *(const u16x8*)&GB[((size_t)(b * P_ + r)) * 2048 + s * 256 + c];
        }
    }
    // ---- one-time: stage encPT a-slice (64 rows x 196 u16, as 98 u16x2)
    for (int it = 0; it < 25; it++) {
        int idx = it * 256 + tid;
        if (idx < 6272) {
            int a = idx / 98, pp = idx - a * 98;
            *(u16x2*)&ePs[a][pp * 2] =
                *(const u16x2*)&encPT[(size_t)(s * 64 + a) * 6272 + b * P_ + pp * 2];
        }
    }
    if (tid < 128)
        *(float4*)&fws[tid * 4] = *(const float4*)&full_W[tid * 4];

    const int lane = tid & 63, wave = tid >> 6;
    const int g16 = lane >> 4, gl = lane & 15;
    const int kg = tid >> 5, cg = tid & 31;
    const float fb0 = full_b[0];
    float c_reg = 0.f;

    // ---- one-time: pin this thread's WhhT slice in registers (256 VGPR)
    u16x8 wreg[64];
    {
        const ushort_t* wp0 = WhhT + (size_t)(kg * 64) * 2048 + s * 256 + cg * 8;
#pragma unroll
        for (int kk = 0; kk < 64; kk++)
            wreg[kk] = *(const u16x8*)&wp0[(size_t)kk * 2048];
    }

    for (int t = 0; t < T_; t++) {
        // ---- acquire h(t)
        if (t == 0) {
            hsh[tid * 2] = 0.f; hsh[tid * 2 + 1] = 0.f;
        } else {
            wait_cnt(hcn, 8u * (unsigned)t);
            const float* hb = hbuf + ((size_t)(t & 1) * 32 + b) * 512;
            hsh[tid * 2] = __hip_atomic_load(&hb[tid * 2],
                                             __ATOMIC_RELAXED, __HIP_MEMORY_SCOPE_AGENT);
            hsh[tid * 2 + 1] = __hip_atomic_load(&hb[tid * 2 + 1],
                                             __ATOMIC_RELAXED, __HIP_MEMORY_SCOPE_AGENT);
        }
        __syncthreads();

        // ---- dps for own a-slice: a_glob = s*64 + a, a in [0,64)
        if (t == 0) {
            if (tid < 64) dps64[tid] = dec_b[s * 64 + tid];
        } else {
#pragma unroll
            for (int q = 0; q < 4; q++) {
                int a = wave * 16 + q * 4 + g16;        // [0,64)
                const ushort_t* wr = decWB + (size_t)(s * 64 + a) * 512;
                float sacc = 0.f;
#pragma unroll
                for (int jj = 0; jj < 4; jj++) {
                    u16x8 wv = *(const u16x8*)&wr[jj * 128 + gl * 8];
                    float4 h0 = *(float4*)&hsh[jj * 128 + gl * 8];
                    float4 h1 = *(float4*)&hsh[jj * 128 + gl * 8 + 4];
                    sacc += b2f(wv[0]) * h0.x + b2f(wv[1]) * h0.y
                          + b2f(wv[2]) * h0.z + b2f(wv[3]) * h0.w
                          + b2f(wv[4]) * h1.x + b2f(wv[5]) * h1.y
                          + b2f(wv[6]) * h1.z + b2f(wv[7]) * h1.w;
                }
                sacc += __shfl_xor(sacc, 1, 64); sacc += __shfl_xor(sacc, 2, 64);
                sacc += __shfl_xor(sacc, 4, 64); sacc += __shfl_xor(sacc, 8, 64);
                if (gl == 0) dps64[a] = sacc + dec_b[s * 64 + a];
            }
        }
        __syncthreads();

        // ---- partial energies over own 64 a's, all from LDS
        if (tid < 196) {
            float e = 0.f;
#pragma unroll 8
            for (int a = 0; a < 64; a++)
                e += fmaxf(b2f(ePs[a][tid]) + dps64[a], 0.f) * fws[s * 64 + a];
            __hip_atomic_store(&epb[s * 200 + tid], e,
                               __ATOMIC_RELAXED, __HIP_MEMORY_SCOPE_AGENT);
        }
        __syncthreads();
        if (tid == 0)
            __hip_atomic_fetch_add(ecn, 1u,
                                   __ATOMIC_RELEASE, __HIP_MEMORY_SCOPE_AGENT);

        // ---- Whh^T.h slice from REGISTERS (overlaps the e-hop round-trip)
        {
            float wa[8] = {0.f,0.f,0.f,0.f,0.f,0.f,0.f,0.f};
#pragma unroll
            for (int kk = 0; kk < 64; kk++) {
                u16x8 wv = wreg[kk];
                float hv = hsh[kg * 64 + kk];
#pragma unroll
                for (int q = 0; q < 8; q++) wa[q] += b2f(wv[q]) * hv;
            }
#pragma unroll
            for (int q = 0; q < 8; q++) sred[kg][cg][q] = wa[q];
        }
        __syncthreads();
        float g = xproj[(size_t)(t * 32 + b) * 2048 + s * 256 + tid];
#pragma unroll
        for (int k2 = 0; k2 < 8; k2++) g += sred[k2][tid >> 3][tid & 7];

        // ---- gather partial energies, reduce, softmax (redundant, cheap)
        wait_cnt(ecn, 8u * (unsigned)(t + 1));
        if (tid < 196) {
            float e = fb0;
#pragma unroll
            for (int s2 = 0; s2 < 8; s2++)
                e += __hip_atomic_load(&epb[s2 * 200 + tid],
                                       __ATOMIC_RELAXED, __HIP_MEMORY_SCOPE_AGENT);
            es[tid] = e;
        }
        __syncthreads();
        if (tid < 64) {
            float v[4]; int pv[4]; int n = 0;
            for (int q = 0; q < 4; q++) {
                int p = tid + 64 * q;
                if (p < P_) { pv[n] = p; v[n] = es[p]; n++; }
            }
            float m = -1e30f;
            for (int q = 0; q < n; q++) m = fmaxf(m, v[q]);
#pragma unroll
            for (int off = 32; off > 0; off >>= 1) m = fmaxf(m, __shfl_xor(m, off, 64));
            float ssum = 0.f;
            for (int q = 0; q < n; q++) { v[q] = expf(v[q] - m); ssum += v[q]; }
#pragma unroll
            for (int off = 32; off > 0; off >>= 1) ssum += __shfl_xor(ssum, off, 64);
            float rinv = 1.f / ssum;
            for (int q = 0; q < n; q++) al[pv[q]] = v[q] * rinv;
        }
        __syncthreads();

        // ---- alpha.G slice (from LDS)
        {
            int p0 = (kg < 4) ? kg * 25 : 100 + (kg - 4) * 24;
            int np = (kg < 4) ? 25 : 24;
            float pa[8] = {0.f,0.f,0.f,0.f,0.f,0.f,0.f,0.f};
#pragma unroll 4
            for (int i = 0; i < np; i++) {
                int p = p0 + i;
                float av = al[p];
                u16x8 gv = *(const u16x8*)&Gs[p][cg * 8];
#pragma unroll
                for (int q = 0; q < 8; q++) pa[q] += b2f(gv[q]) * av;
            }
#pragma unroll
            for (int q = 0; q < 8; q++) sred[kg][cg][q] = pa[q];
        }
        __syncthreads();
#pragma unroll
        for (int k2 = 0; k2 < 8; k2++) g += sred[k2][tid >> 3][tid & 7];
        gsh[tid] = g;
        __syncthreads();

        // ---- block-local pointwise LSTM for this block's 64 hidden units
        if (tid < 64) {
            int ri = tid >> 3, e = tid & 7;
            float gi = gsh[ri * 32 + e];
            float gf = gsh[ri * 32 + 8 + e];
            float gg = gsh[ri * 32 + 16 + e];
            float go = gsh[ri * 32 + 24 + e];
            float ig = 1.f / (1.f + expf(-gi));
            float fg = 1.f / (1.f + expf(-gf));
            float g_ = tanhf(gg);
            float og = 1.f / (1.f + expf(-go));
            c_reg = fg * c_reg + ig * g_;
            float hn = og * tanhf(c_reg);
            int u = 8 * s + 64 * ri + e;
            float* ho = hbuf + ((size_t)((t + 1) & 1) * 32 + b) * 512 + u;
            __hip_atomic_store(ho, hn, __ATOMIC_RELAXED, __HIP_MEMORY_SCOPE_AGENT);
            hseqB[(size_t)(t + 1) * 16384 + b * 512 + u] = bf_rne(hn);
        }
        __syncthreads();
        if (tid == 0)
            __hip_atomic_fetch_add(hcn, 1u,
                                   __ATOMIC_RELEASE, __HIP_MEMORY_SCOPE_AGENT);
    }
}

// ---------------------------------------------------------------------------
extern "C" void kernel_launch(void* const* d_in, const int* in_sizes, int n_in,
                              void* d_out, int out_size, void* d_ws, size_t ws_size,
                              hipStream_t stream)
{
    (void)in_sizes; (void)n_in; (void)out_size; (void)ws_size;
    const float* feat   = (const float*)d_in[0];
    const int*   caps   = (const int*)  d_in[1];
    const float* emb    = (const float*)d_in[2];
    const float* W_ih   = (const float*)d_in[3];
    const float* b_ih   = (const float*)d_in[4];
    const float* W_hh   = (const float*)d_in[5];
    const float* b_hh   = (const float*)d_in[6];
    const float* fc_W   = (const float*)d_in[7];
    const float* fc_b   = (const float*)d_in[8];
    const float* enc_W  = (const float*)d_in[9];
    const float* enc_b  = (const float*)d_in[10];
    const float* dec_W  = (const float*)d_in[11];
    const float* dec_b  = (const float*)d_in[12];
    const float* full_W = (const float*)d_in[13];
    const float* full_b = (const float*)d_in[14];
    float* out = (float*)d_out;

    // workspace carve (~90 MB), 128B-aligned chunks
    char* w = (char*)d_ws;
    ushort_t* featB = (ushort_t*)w;              w += 25690112;  // [6272][2048]
    ushort_t* encWB = (ushort_t*)w;              w += 2097152;   // [512][2048]
    ushort_t* fcWB  = (ushort_t*)w;              w += 10240000;  // [10000][512]
    ushort_t* decWB = (ushort_t*)w;              w += 524288;    // [512][512]
    ushort_t* WihCB = (ushort_t*)w;              w += 8388608;   // [2048][2048] (rows permuted)
    ushort_t* WihEB = (ushort_t*)w;              w += 2097152;   // [2048][512]  (rows permuted)
    ushort_t* WhhT  = (ushort_t*)w;              w += 2097152;   // [512][2048]  (cols permuted)
    ushort_t* XB    = (ushort_t*)w;              w += 655360;    // [640][512]
    ushort_t* encPT = (ushort_t*)w;              w += 6422528;   // [512][6272] a-major
    ushort_t* GB    = (ushort_t*)w;              w += 25690112;  // [6272][2048] (cols permuted)
    float*    xproj = (float*)w;                 w += 5242880;   // [640][2048]  (cols permuted)
    float*    bsum  = (float*)w;                 w += 8192;      // [2048] (permuted)
    float*    zbuf  = (float*)w;                 w += 8192;      // [2048]
    float*    hbuf  = (float*)w;                 w += 131072;    // [2][32][512]
    ushort_t* hseqB = (ushort_t*)w;              w += 688128;    // [21][32][512]
    unsigned* hcnt  = (unsigned*)w;              w += 4096;      // [32][32]
    unsigned* ecnt  = (unsigned*)w;              w += 4096;      // [32][32]
    float*    epartG= (float*)w;                 w += 204800;    // [32][8][200]

    // zero per-b sync counters (hcnt+ecnt adjacent; ws re-poisoned each replay)
    hipMemsetAsync(hcnt, 0, 8192, stream);

    // one-time converts / extracts / transposes / gathers / permutes (1 node)
    cvt_all_kernel<<<13125, 256, 0, stream>>>(
        feat, enc_W, fc_W, dec_W, W_ih, W_hh, emb, caps, b_ih, b_hh,
        featB, encWB, fcWB, decWB, WihCB, WihEB, WhhT, XB, bsum, zbuf);

    // enc_proj TRANSPOSED: [512,2048]x[6272,2048]^T -> encPT[a][b*196+p] bf16
    // (row bias enc_b[a] via mode 3)
    mfma_gemm_kernel<<<dim3(4, 49), 256, 0, stream>>>(
        encWB, featB, enc_b, encPT, nullptr, 2048, 6272, 3);

    // G = feat . W_ihC^T (rows of WihCB permuted -> GB cols permuted) bf16
    mfma_gemm_kernel<<<dim3(49, 16), 256, 0, stream>>>(
        featB, WihCB, zbuf, GB, nullptr, 2048, 2048, 0);

    // xproj = X . W_ihE^T + bsum (cols permuted to match)
    mfma_gemm_kernel<<<dim3(5, 16), 256, 0, stream>>>(
        XB, WihEB, bsum, nullptr, xproj, 512, 2048, 2);

    // persistent 20-step recurrent loop: 2 relaxed hops/step, pinned operands
    persist_kernel<<<NBLK, 256, 0, stream>>>(
        hbuf, hseqB, encPT, decWB, dec_b, full_W, full_b,
        GB, WhhT, xproj, epartG, hcnt, ecnt);

    // batched vocab FC: [640,512]x[10000,512]^T -> out (f32, remapped rows)
    mfma_gemm_kernel<<<dim3(5, 79), 256, 0, stream>>>(
        hseqB + 16384, fcWB, fc_b, nullptr, out, 512, V_, 1);
}

// Round 5
// 840.469 us; speedup vs baseline: 1.0445x; 1.0445x over previous
//
#include <hip/hip_runtime.h>
#include <math.h>

#define B_   32
#define P_   196
#define F_   2048
#define E_   512
#define H_   512
#define V_   10000
#define T_   20
#define GSZ  8            // blocks per batch-element group
#define NBLK (B_ * GSZ)   // 256 persistent blocks = 1 per CU (LDS-limited)

typedef unsigned short ushort_t;
typedef ushort_t u16x8 __attribute__((ext_vector_type(8)));
typedef ushort_t u16x2 __attribute__((ext_vector_type(2)));
typedef short    bf16x8 __attribute__((ext_vector_type(8)));
typedef float    f32x4  __attribute__((ext_vector_type(4)));

__device__ __forceinline__ ushort_t bf_rne(float x) {
    union { float f; unsigned u; } v; v.f = x;
    unsigned r = v.u + 0x7FFFu + ((v.u >> 16) & 1u);
    return (ushort_t)(r >> 16);
}
__device__ __forceinline__ float b2f(ushort_t u) {
    union { unsigned u; float f; } v; v.u = ((unsigned)u) << 16;
    return v.f;
}

// async global->LDS, 16B per lane. LDS dest is wave-uniform base + lane*16.
__device__ __forceinline__ void gl_lds16(const ushort_t* g, ushort_t* l) {
    __builtin_amdgcn_global_load_lds(
        (const __attribute__((address_space(1))) void*)g,
        (__attribute__((address_space(3))) void*)l, 16, 0, 0);
}

// Column permutation: g-col j -> P(j) = s_own*256 + ri*32 + gi*8 + e.
// chunk=j>>3, gi=chunk>>6 (gate), r=chunk&63, owner=r&7, ri=r>>3, e=j&7.
// Gate stride 512 = 64 chunks -> all 4 gates of one hidden unit share owner.
__device__ __forceinline__ int permc(int chunk) {   // chunk in [0,256) -> new chunk
    int gi = chunk >> 6, r = chunk & 63;
    return (r & 7) * 32 + (r >> 3) * 4 + gi;
}

// ---------------------------------------------------------------------------
// One-time conversion mega-kernel (1 node): bf16 converts / extracts /
// transposes / caption-gather / g-col permutations. 13125 blocks x 256 thr.
// ---------------------------------------------------------------------------
__global__ __launch_bounds__(256)
void cvt_all_kernel(const float* __restrict__ feat, const float* __restrict__ enc_W,
                    const float* __restrict__ fc_W, const float* __restrict__ dec_W,
                    const float* __restrict__ W_ih, const float* __restrict__ W_hh,
                    const float* __restrict__ emb, const int* __restrict__ captions,
                    const float* __restrict__ b_ih, const float* __restrict__ b_hh,
                    ushort_t* __restrict__ featB, ushort_t* __restrict__ encWB,
                    ushort_t* __restrict__ fcWB, ushort_t* __restrict__ decWB,
                    ushort_t* __restrict__ WihCB, ushort_t* __restrict__ WihEB,
                    ushort_t* __restrict__ WhhT, ushort_t* __restrict__ XB,
                    float* __restrict__ bsum, float* __restrict__ zbuf)
{
    const int blk = blockIdx.x, tid = threadIdx.x;
    if (blk < 6272) {                       // featB flat
        size_t i = (size_t)blk * 2048 + tid * 8;
        float4 a = *(const float4*)&feat[i], b = *(const float4*)&feat[i + 4];
        u16x8 o; o[0]=bf_rne(a.x); o[1]=bf_rne(a.y); o[2]=bf_rne(a.z); o[3]=bf_rne(a.w);
        o[4]=bf_rne(b.x); o[5]=bf_rne(b.y); o[6]=bf_rne(b.z); o[7]=bf_rne(b.w);
        *(u16x8*)&featB[i] = o;
    } else if (blk < 6784) {                // encWB
        size_t i = (size_t)(blk - 6272) * 2048 + tid * 8;
        float4 a = *(const float4*)&enc_W[i], b = *(const float4*)&enc_W[i + 4];
        u16x8 o; o[0]=bf_rne(a.x); o[1]=bf_rne(a.y); o[2]=bf_rne(a.z); o[3]=bf_rne(a.w);
        o[4]=bf_rne(b.x); o[5]=bf_rne(b.y); o[6]=bf_rne(b.z); o[7]=bf_rne(b.w);
        *(u16x8*)&encWB[i] = o;
    } else if (blk < 9284) {                // fcWB
        size_t i = (size_t)(blk - 6784) * 2048 + tid * 8;
        float4 a = *(const float4*)&fc_W[i], b = *(const float4*)&fc_W[i + 4];
        u16x8 o; o[0]=bf_rne(a.x); o[1]=bf_rne(a.y); o[2]=bf_rne(a.z); o[3]=bf_rne(a.w);
        o[4]=bf_rne(b.x); o[5]=bf_rne(b.y); o[6]=bf_rne(b.z); o[7]=bf_rne(b.w);
        *(u16x8*)&fcWB[i] = o;
    } else if (blk < 9412) {                // decWB
        size_t i = (size_t)(blk - 9284) * 2048 + tid * 8;
        float4 a = *(const float4*)&dec_W[i], b = *(const float4*)&dec_W[i + 4];
        u16x8 o; o[0]=bf_rne(a.x); o[1]=bf_rne(a.y); o[2]=bf_rne(a.z); o[3]=bf_rne(a.w);
        o[4]=bf_rne(b.x); o[5]=bf_rne(b.y); o[6]=bf_rne(b.z); o[7]=bf_rne(b.w);
        *(u16x8*)&decWB[i] = o;
    } else if (blk < 11460) {               // WihCB[P(j)] = bf16(W_ih[j, 512:2560])
        int j = blk - 9412, f = tid * 8;
        int Pj = permc(j >> 3) * 8 + (j & 7);
        const float* s = &W_ih[(size_t)j * 2560 + 512 + f];
        float4 a = *(const float4*)&s[0], b = *(const float4*)&s[4];
        u16x8 o; o[0]=bf_rne(a.x); o[1]=bf_rne(a.y); o[2]=bf_rne(a.z); o[3]=bf_rne(a.w);
        o[4]=bf_rne(b.x); o[5]=bf_rne(b.y); o[6]=bf_rne(b.z); o[7]=bf_rne(b.w);
        *(u16x8*)&WihCB[(size_t)Pj * 2048 + f] = o;
    } else if (blk < 11972) {               // WihEB[P(j)] = bf16(W_ih[j, 0:512])
        size_t idx = (size_t)(blk - 11460) * 2048 + tid * 8;
        int j = (int)(idx >> 9), f = (int)(idx & 511);
        int Pj = permc(j >> 3) * 8 + (j & 7);
        const float* s = &W_ih[(size_t)j * 2560 + f];
        float4 a = *(const float4*)&s[0], b = *(const float4*)&s[4];
        u16x8 o; o[0]=bf_rne(a.x); o[1]=bf_rne(a.y); o[2]=bf_rne(a.z); o[3]=bf_rne(a.w);
        o[4]=bf_rne(b.x); o[5]=bf_rne(b.y); o[6]=bf_rne(b.z); o[7]=bf_rne(b.w);
        *(u16x8*)&WihEB[(size_t)Pj * 512 + f] = o;
    } else if (blk < 12484) {               // WhhT[k][P(j)] = bf16(W_hh[j][k])
        int k = blk - 11972, j0 = tid * 8;
        int nc = permc(tid);
        u16x8 o;
#pragma unroll
        for (int q = 0; q < 8; q++) o[q] = bf_rne(W_hh[(size_t)(j0 + q) * 512 + k]);
        *(u16x8*)&WhhT[(size_t)k * 2048 + nc * 8] = o;
    } else if (blk < 13124) {               // XB[m] = bf16(emb[captions]), m = t*32+b
        int m = blk - 12484;
        int tt = m >> 5, b = m & 31;
        int cap = captions[b * T_ + tt];
        int i = tid * 2;
        u16x2 o;
        o[0] = bf_rne(emb[(size_t)cap * 512 + i]);
        o[1] = bf_rne(emb[(size_t)cap * 512 + i + 1]);
        *(u16x2*)&XB[(size_t)m * 512 + i] = o;
    } else {                                // bsum (permuted) + zbuf
        int nc = permc(tid);
        int j0 = tid * 8;
#pragma unroll
        for (int q = 0; q < 8; q++) {
            bsum[nc * 8 + q] = b_ih[j0 + q] + b_hh[j0 + q];
            zbuf[j0 + q] = 0.f;
        }
    }
}

// ---------------------------------------------------------------------------
// bf16 MFMA GEMM: C[m,n] = A[m,:].B[n,:] + bias, A/B bf16 K-major.
// 128x128 tile, 4 waves, 4x4 of 16x16x32 MFMA per wave.
// Staging via global_load_lds width=16 (linear LDS layout, wave-uniform base).
// mode 0: bf16 store, bias[n].  mode 1: f32 store, crow=(m&31)*20+(m>>5).
// mode 2: f32 store plain.      mode 3: bf16 store, ROW bias[m].
// ---------------------------------------------------------------------------
__global__ __launch_bounds__(256)
void mfma_gemm_kernel(const ushort_t* __restrict__ A, const ushort_t* __restrict__ B,
                      const float* __restrict__ bias, ushort_t* __restrict__ Cb,
                      float* __restrict__ Cf, int K, int N, int mode)
{
    __shared__ ushort_t As[128][32];
    __shared__ ushort_t Bs[128][32];
    const int tid = threadIdx.x;
    const int m0 = blockIdx.x * 128, n0 = blockIdx.y * 128;
    const int wave = tid >> 6, lane = tid & 63;
    const int wm = (wave & 1) * 64, wn = (wave >> 1) * 64;
    const int lm = lane & 15, lk = (lane >> 4) * 8;

    f32x4 acc[4][4];
#pragma unroll
    for (int mt = 0; mt < 4; mt++)
#pragma unroll
        for (int nt = 0; nt < 4; nt++)
#pragma unroll
            for (int r = 0; r < 4; r++) acc[mt][nt][r] = 0.f;

    for (int k0 = 0; k0 < K; k0 += 32) {
#pragma unroll
        for (int i = 0; i < 2; i++) {
            int gi  = tid + i * 256;
            int row = gi >> 2;
            int gr  = (gi & 3) * 8;
            // LDS offset for this lane is gi*16B = wave-uniform base + lane*16B
            ushort_t* lbA = &As[0][0] + (size_t)(wave * 64 + i * 256) * 8;
            ushort_t* lbB = &Bs[0][0] + (size_t)(wave * 64 + i * 256) * 8;
            gl_lds16(&A[(size_t)(m0 + row) * K + k0 + gr], lbA);
            int brow = n0 + row; if (brow >= N) brow = N - 1;
            gl_lds16(&B[(size_t)brow * K + k0 + gr], lbB);
        }
        __syncthreads();
        bf16x8 af[4], bv[4];
#pragma unroll
        for (int mt = 0; mt < 4; mt++)
            af[mt] = *(const bf16x8*)&As[wm + mt * 16 + lm][lk];
#pragma unroll
        for (int nt = 0; nt < 4; nt++)
            bv[nt] = *(const bf16x8*)&Bs[wn + nt * 16 + lm][lk];
#pragma unroll
        for (int mt = 0; mt < 4; mt++)
#pragma unroll
            for (int nt = 0; nt < 4; nt++)
                acc[mt][nt] = __builtin_amdgcn_mfma_f32_16x16x32_bf16(
                    af[mt], bv[nt], acc[mt][nt], 0, 0, 0);
        __syncthreads();
    }

    const int rb = (lane >> 4) * 4;
#pragma unroll
    for (int nt = 0; nt < 4; nt++) {
        int n = n0 + wn + nt * 16 + lm;
        int nc = n < N ? n : N - 1;
        float bz = (mode == 3) ? 0.f : bias[nc];
#pragma unroll
        for (int mt = 0; mt < 4; mt++) {
            int mbase = m0 + wm + mt * 16 + rb;
#pragma unroll
            for (int r = 0; r < 4; r++) {
                int m = mbase + r;
                float v = acc[mt][nt][r] + ((mode == 3) ? bias[m] : bz);
                if (mode == 0 || mode == 3) {
                    Cb[(size_t)m * N + n] = bf_rne(v);
                } else if (n < N) {
                    int crow = (mode == 1) ? ((m & 31) * 20 + (m >> 5)) : m;
                    Cf[(size_t)crow * N + n] = v;
                }
            }
        }
    }
}

// Relaxed-only poll: NO acquire -> no L2 invalidate, weights stay L2-hot.
// Cross-block payloads move via agent-scope relaxed atomic load/store.
__device__ __forceinline__ void wait_cnt(unsigned* p, unsigned target) {
    if (threadIdx.x == 0) {
        while (__hip_atomic_load(p, __ATOMIC_RELAXED, __HIP_MEMORY_SCOPE_AGENT) < target)
            __builtin_amdgcn_s_sleep(1);
    }
    __syncthreads();
}

// ---------------------------------------------------------------------------
// Persistent 20-step decoder. 256 blocks = 32 groups x 8. Block (b,s):
//  - owns 256 permuted g-cols: Whh.h slice (WhhT streamed from L2 —
//    latency-tolerant, overlaps the e-hop), alpha.G slice (G in LDS, staged
//    once), local pointwise (c in regs).
//  - owns attention a-slice [s*64,s*64+64): decW rows PINNED IN REGISTERS
//    (16 x u16x8 = 64 VGPR/thread; fits arch-256 budget, round-4's 256-VGPR
//    wreg spilled to scratch) and encPT slice PINNED IN LDS (25.6 KB) ->
//    dps + energies are pure regs/LDS, zero L2 latency on critical path.
// Per step: xproj prefetch, h-hop, dps (regs), energies (LDS), publish epart,
// Whh.h (L2 stream, overlaps e-hop), gather+softmax, alpha.G (LDS),
// pointwise, publish h.
// ---------------------------------------------------------------------------
__global__ __launch_bounds__(256, 1)
void persist_kernel(float* __restrict__ hbuf,           // [2][32][512]
                    ushort_t* __restrict__ hseqB,       // [21][32][512]
                    const ushort_t* __restrict__ encPT, // [512][6272] a-major
                    const ushort_t* __restrict__ decWB, // [512][512]
                    const float* __restrict__ dec_b,
                    const float* __restrict__ full_W,
                    const float* __restrict__ full_b,
                    const ushort_t* __restrict__ GB,    // [6272][2048] col-permuted
                    const ushort_t* __restrict__ WhhT,  // [512][2048] col-permuted
                    const float* __restrict__ xproj,    // [640][2048] col-permuted
                    float* __restrict__ epartG,         // [32][8][200]
                    unsigned* __restrict__ hcnt,        // [32][32]
                    unsigned* __restrict__ ecnt)        // [32][32]
{
    __shared__ ushort_t Gs[196][256];   // 100,352 B: this block's G col-slice
    __shared__ ushort_t ePs[64][200];   // 25,600 B: this block's encPT a-slice
    __shared__ float hsh[512];
    __shared__ float fws[512];
    __shared__ float dps64[64];
    __shared__ float es[200];
    __shared__ float al[200];
    __shared__ float sred[8][32][9];    // padded: conflict-free reduce scratch
    __shared__ float gsh[256];

    const int tid = threadIdx.x;
    const int b = blockIdx.x & 31;      // all 8 blocks of b -> same XCD
    const int s = blockIdx.x >> 5;
    unsigned* hcn = &hcnt[b * 32];
    unsigned* ecn = &ecnt[b * 32];
    float* epb = epartG + (size_t)b * 1600;

    // ---- one-time: stage this block's (contiguous, permuted) G slice
    {
        const int r0 = tid >> 5, c = (tid & 31) * 8;
        for (int i = 0; i < 25; i++) {
            int r = i * 8 + r0;
            if (r < 196)
                *(u16x8*)&Gs[r][c] =
                    *(const u16x8*)&GB[((size_t)(b * P_ + r)) * 2048 + s * 256 + c];
        }
    }
    // ---- one-time: stage encPT a-slice (64 rows x 196 u16, as 98 u16x2)
    for (int it = 0; it < 25; it++) {
        int idx = it * 256 + tid;
        if (idx < 6272) {
            int a = idx / 98, pp = idx - a * 98;
            *(u16x2*)&ePs[a][pp * 2] =
                *(const u16x2*)&encPT[(size_t)(s * 64 + a) * 6272 + b * P_ + pp * 2];
        }
    }
    if (tid < 128)
        *(float4*)&fws[tid * 4] = *(const float4*)&full_W[tid * 4];

    const int lane = tid & 63, wave = tid >> 6;
    const int g16 = lane >> 4, gl = lane & 15;
    const int kg = tid >> 5, cg = tid & 31;
    const float fb0 = full_b[0];
    float c_reg = 0.f;

    // ---- one-time: pin this thread's decW dps-slice in registers (64 VGPR)
    // dreg[q*4+jj] = decWB[(s*64 + wave*16 + q*4 + g16)*512 + jj*128 + gl*8]
    u16x8 dreg[16];
#pragma unroll
    for (int q = 0; q < 4; q++) {
        int a = wave * 16 + q * 4 + g16;
        const ushort_t* wr = decWB + (size_t)(s * 64 + a) * 512;
#pragma unroll
        for (int jj = 0; jj < 4; jj++)
            dreg[q * 4 + jj] = *(const u16x8*)&wr[jj * 128 + gl * 8];
    }

    for (int t = 0; t < T_; t++) {
        // ---- prefetch xproj for this step (independent of h; hides under hop)
        float gx = xproj[(size_t)(t * 32 + b) * 2048 + s * 256 + tid];

        // ---- acquire h(t)
        if (t == 0) {
            hsh[tid * 2] = 0.f; hsh[tid * 2 + 1] = 0.f;
        } else {
            wait_cnt(hcn, 8u * (unsigned)t);
            const float* hb = hbuf + ((size_t)(t & 1) * 32 + b) * 512;
            hsh[tid * 2] = __hip_atomic_load(&hb[tid * 2],
                                             __ATOMIC_RELAXED, __HIP_MEMORY_SCOPE_AGENT);
            hsh[tid * 2 + 1] = __hip_atomic_load(&hb[tid * 2 + 1],
                                             __ATOMIC_RELAXED, __HIP_MEMORY_SCOPE_AGENT);
        }
        __syncthreads();

        // ---- dps for own a-slice from REGISTERS: a_glob = s*64 + a
        if (t == 0) {
            if (tid < 64) dps64[tid] = dec_b[s * 64 + tid];
        } else {
#pragma unroll
            for (int q = 0; q < 4; q++) {
                int a = wave * 16 + q * 4 + g16;        // [0,64)
                float sacc = 0.f;
#pragma unroll
                for (int jj = 0; jj < 4; jj++) {
                    u16x8 wv = dreg[q * 4 + jj];
                    float4 h0 = *(float4*)&hsh[jj * 128 + gl * 8];
                    float4 h1 = *(float4*)&hsh[jj * 128 + gl * 8 + 4];
                    sacc += b2f(wv[0]) * h0.x + b2f(wv[1]) * h0.y
                          + b2f(wv[2]) * h0.z + b2f(wv[3]) * h0.w
                          + b2f(wv[4]) * h1.x + b2f(wv[5]) * h1.y
                          + b2f(wv[6]) * h1.z + b2f(wv[7]) * h1.w;
                }
                sacc += __shfl_xor(sacc, 1, 64); sacc += __shfl_xor(sacc, 2, 64);
                sacc += __shfl_xor(sacc, 4, 64); sacc += __shfl_xor(sacc, 8, 64);
                if (gl == 0) dps64[a] = sacc + dec_b[s * 64 + a];
            }
        }
        __syncthreads();

        // ---- partial energies over own 64 a's, all from LDS
        if (tid < 196) {
            float e = 0.f;
#pragma unroll 8
            for (int a = 0; a < 64; a++)
                e += fmaxf(b2f(ePs[a][tid]) + dps64[a], 0.f) * fws[s * 64 + a];
            __hip_atomic_store(&epb[s * 200 + tid], e,
                               __ATOMIC_RELAXED, __HIP_MEMORY_SCOPE_AGENT);
        }
        __syncthreads();
        if (tid == 0)
            __hip_atomic_fetch_add(ecn, 1u,
                                   __ATOMIC_RELEASE, __HIP_MEMORY_SCOPE_AGENT);

        // ---- Whh^T.h slice from L2 (latency-tolerant, overlaps the e-hop)
        {
            float wa[8] = {0.f,0.f,0.f,0.f,0.f,0.f,0.f,0.f};
            const ushort_t* wp = WhhT + (size_t)(kg * 64) * 2048 + s * 256 + cg * 8;
#pragma unroll 8
            for (int kk = 0; kk < 64; kk++) {
                u16x8 wv = *(const u16x8*)&wp[(size_t)kk * 2048];
                float hv = hsh[kg * 64 + kk];
#pragma unroll
                for (int q = 0; q < 8; q++) wa[q] += b2f(wv[q]) * hv;
            }
#pragma unroll
            for (int q = 0; q < 8; q++) sred[kg][cg][q] = wa[q];
        }
        __syncthreads();
        float g = gx;
#pragma unroll
        for (int k2 = 0; k2 < 8; k2++) g += sred[k2][tid >> 3][tid & 7];

        // ---- gather partial energies, reduce, softmax (redundant, cheap)
        wait_cnt(ecn, 8u * (unsigned)(t + 1));
        if (tid < 196) {
            float e = fb0;
#pragma unroll
            for (int s2 = 0; s2 < 8; s2++)
                e += __hip_atomic_load(&epb[s2 * 200 + tid],
                                       __ATOMIC_RELAXED, __HIP_MEMORY_SCOPE_AGENT);
            es[tid] = e;
        }
        __syncthreads();
        if (tid < 64) {
            float v[4]; int pv[4]; int n = 0;
            for (int q = 0; q < 4; q++) {
                int p = tid + 64 * q;
                if (p < P_) { pv[n] = p; v[n] = es[p]; n++; }
            }
            float m = -1e30f;
            for (int q = 0; q < n; q++) m = fmaxf(m, v[q]);
#pragma unroll
            for (int off = 32; off > 0; off >>= 1) m = fmaxf(m, __shfl_xor(m, off, 64));
            float ssum = 0.f;
            for (int q = 0; q < n; q++) { v[q] = expf(v[q] - m); ssum += v[q]; }
#pragma unroll
            for (int off = 32; off > 0; off >>= 1) ssum += __shfl_xor(ssum, off, 64);
            float rinv = 1.f / ssum;
            for (int q = 0; q < n; q++) al[pv[q]] = v[q] * rinv;
        }
        __syncthreads();

        // ---- alpha.G slice (from LDS)
        {
            int p0 = (kg < 4) ? kg * 25 : 100 + (kg - 4) * 24;
            int np = (kg < 4) ? 25 : 24;
            float pa[8] = {0.f,0.f,0.f,0.f,0.f,0.f,0.f,0.f};
#pragma unroll 4
            for (int i = 0; i < np; i++) {
                int p = p0 + i;
                float av = al[p];
                u16x8 gv = *(const u16x8*)&Gs[p][cg * 8];
#pragma unroll
                for (int q = 0; q < 8; q++) pa[q] += b2f(gv[q]) * av;
            }
#pragma unroll
            for (int q = 0; q < 8; q++) sred[kg][cg][q] = pa[q];
        }
        __syncthreads();
#pragma unroll
        for (int k2 = 0; k2 < 8; k2++) g += sred[k2][tid >> 3][tid & 7];
        gsh[tid] = g;
        __syncthreads();

        // ---- block-local pointwise LSTM for this block's 64 hidden units
        if (tid < 64) {
            int ri = tid >> 3, e = tid & 7;
            float gi = gsh[ri * 32 + e];
            float gf = gsh[ri * 32 + 8 + e];
            float gg = gsh[ri * 32 + 16 + e];
            float go = gsh[ri * 32 + 24 + e];
            float ig = 1.f / (1.f + expf(-gi));
            float fg = 1.f / (1.f + expf(-gf));
            float g_ = tanhf(gg);
            float og = 1.f / (1.f + expf(-go));
            c_reg = fg * c_reg + ig * g_;
            float hn = og * tanhf(c_reg);
            int u = 8 * s + 64 * ri + e;
            float* ho = hbuf + ((size_t)((t + 1) & 1) * 32 + b) * 512 + u;
            __hip_atomic_store(ho, hn, __ATOMIC_RELAXED, __HIP_MEMORY_SCOPE_AGENT);
            hseqB[(size_t)(t + 1) * 16384 + b * 512 + u] = bf_rne(hn);
        }
        __syncthreads();
        if (tid == 0)
            __hip_atomic_fetch_add(hcn, 1u,
                                   __ATOMIC_RELEASE, __HIP_MEMORY_SCOPE_AGENT);
    }
}

// ---------------------------------------------------------------------------
extern "C" void kernel_launch(void* const* d_in, const int* in_sizes, int n_in,
                              void* d_out, int out_size, void* d_ws, size_t ws_size,
                              hipStream_t stream)
{
    (void)in_sizes; (void)n_in; (void)out_size; (void)ws_size;
    const float* feat   = (const float*)d_in[0];
    const int*   caps   = (const int*)  d_in[1];
    const float* emb    = (const float*)d_in[2];
    const float* W_ih   = (const float*)d_in[3];
    const float* b_ih   = (const float*)d_in[4];
    const float* W_hh   = (const float*)d_in[5];
    const float* b_hh   = (const float*)d_in[6];
    const float* fc_W   = (const float*)d_in[7];
    const float* fc_b   = (const float*)d_in[8];
    const float* enc_W  = (const float*)d_in[9];
    const float* enc_b  = (const float*)d_in[10];
    const float* dec_W  = (const float*)d_in[11];
    const float* dec_b  = (const float*)d_in[12];
    const float* full_W = (const float*)d_in[13];
    const float* full_b = (const float*)d_in[14];
    float* out = (float*)d_out;

    // workspace carve (~90 MB), 128B-aligned chunks
    char* w = (char*)d_ws;
    ushort_t* featB = (ushort_t*)w;              w += 25690112;  // [6272][2048]
    ushort_t* encWB = (ushort_t*)w;              w += 2097152;   // [512][2048]
    ushort_t* fcWB  = (ushort_t*)w;              w += 10240000;  // [10000][512]
    ushort_t* decWB = (ushort_t*)w;              w += 524288;    // [512][512]
    ushort_t* WihCB = (ushort_t*)w;              w += 8388608;   // [2048][2048] (rows permuted)
    ushort_t* WihEB = (ushort_t*)w;              w += 2097152;   // [2048][512]  (rows permuted)
    ushort_t* WhhT  = (ushort_t*)w;              w += 2097152;   // [512][2048]  (cols permuted)
    ushort_t* XB    = (ushort_t*)w;              w += 655360;    // [640][512]
    ushort_t* encPT = (ushort_t*)w;              w += 6422528;   // [512][6272] a-major
    ushort_t* GB    = (ushort_t*)w;              w += 25690112;  // [6272][2048] (cols permuted)
    float*    xproj = (float*)w;                 w += 5242880;   // [640][2048]  (cols permuted)
    float*    bsum  = (float*)w;                 w += 8192;      // [2048] (permuted)
    float*    zbuf  = (float*)w;                 w += 8192;      // [2048]
    float*    hbuf  = (float*)w;                 w += 131072;    // [2][32][512]
    ushort_t* hseqB = (ushort_t*)w;              w += 688128;    // [21][32][512]
    unsigned* hcnt  = (unsigned*)w;              w += 4096;      // [32][32]
    unsigned* ecnt  = (unsigned*)w;              w += 4096;      // [32][32]
    float*    epartG= (float*)w;                 w += 204800;    // [32][8][200]

    // zero per-b sync counters (hcnt+ecnt adjacent; ws re-poisoned each replay)
    hipMemsetAsync(hcnt, 0, 8192, stream);

    // one-time converts / extracts / transposes / gathers / permutes (1 node)
    cvt_all_kernel<<<13125, 256, 0, stream>>>(
        feat, enc_W, fc_W, dec_W, W_ih, W_hh, emb, caps, b_ih, b_hh,
        featB, encWB, fcWB, decWB, WihCB, WihEB, WhhT, XB, bsum, zbuf);

    // enc_proj TRANSPOSED: [512,2048]x[6272,2048]^T -> encPT[a][b*196+p] bf16
    // (row bias enc_b[a] via mode 3)
    mfma_gemm_kernel<<<dim3(4, 49), 256, 0, stream>>>(
        encWB, featB, enc_b, encPT, nullptr, 2048, 6272, 3);

    // G = feat . W_ihC^T (rows of WihCB permuted -> GB cols permuted) bf16
    mfma_gemm_kernel<<<dim3(49, 16), 256, 0, stream>>>(
        featB, WihCB, zbuf, GB, nullptr, 2048, 2048, 0);

    // xproj = X . W_ihE^T + bsum (cols permuted to match)
    mfma_gemm_kernel<<<dim3(5, 16), 256, 0, stream>>>(
        XB, WihEB, bsum, nullptr, xproj, 512, 2048, 2);

    // persistent 20-step recurrent loop: 2 relaxed hops/step, pinned operands
    persist_kernel<<<NBLK, 256, 0, stream>>>(
        hbuf, hseqB, encPT, decWB, dec_b, full_W, full_b,
        GB, WhhT, xproj, epartG, hcnt, ecnt);

    // batched vocab FC: [640,512]x[10000,512]^T -> out (f32, remapped rows)
    mfma_gemm_kernel<<<dim3(5, 79), 256, 0, stream>>>(
        hseqB + 16384, fcWB, fc_b, nullptr, out, 512, V_, 1);
}

// Round 6
// 733.719 us; speedup vs baseline: 1.1965x; 1.1455x over previous
//
#include <hip/hip_runtime.h>
#include <math.h>

#define B_   32
#define P_   196
#define F_   2048
#define E_   512
#define H_   512
#define V_   10000
#define T_   20
#define GSZ  8            // blocks per batch-element group
#define NBLK (B_ * GSZ)   // 256 persistent blocks = 1 per CU (LDS-limited)

typedef unsigned short ushort_t;
typedef unsigned long long u64_t;
typedef ushort_t u16x8 __attribute__((ext_vector_type(8)));
typedef ushort_t u16x2 __attribute__((ext_vector_type(2)));
typedef short    bf16x8 __attribute__((ext_vector_type(8)));
typedef float    f32x4  __attribute__((ext_vector_type(4)));

__device__ __forceinline__ ushort_t bf_rne(float x) {
    union { float f; unsigned u; } v; v.f = x;
    unsigned r = v.u + 0x7FFFu + ((v.u >> 16) & 1u);
    return (ushort_t)(r >> 16);
}
__device__ __forceinline__ float b2f(ushort_t u) {
    union { unsigned u; float f; } v; v.u = ((unsigned)u) << 16;
    return v.f;
}
__device__ __forceinline__ unsigned f2u(float f) {
    union { float f; unsigned u; } v; v.f = f; return v.u;
}
__device__ __forceinline__ float u2f(unsigned u) {
    union { unsigned u; float f; } v; v.u = u; return v.f;
}

// async global->LDS, 16B per lane. LDS dest is wave-uniform base + lane*16.
__device__ __forceinline__ void gl_lds16(const ushort_t* g, ushort_t* l) {
    __builtin_amdgcn_global_load_lds(
        (const __attribute__((address_space(1))) void*)g,
        (__attribute__((address_space(3))) void*)l, 16, 0, 0);
}

// Column permutation: g-col j -> P(j) = s_own*256 + ri*32 + gi*8 + e.
// chunk=j>>3, gi=chunk>>6 (gate), r=chunk&63, owner=r&7, ri=r>>3, e=j&7.
// Gate stride 512 = 64 chunks -> all 4 gates of one hidden unit share owner.
__device__ __forceinline__ int permc(int chunk) {   // chunk in [0,256) -> new chunk
    int gi = chunk >> 6, r = chunk & 63;
    return (r & 7) * 32 + (r >> 3) * 4 + gi;
}

// ---------------------------------------------------------------------------
// One-time conversion mega-kernel (1 node): bf16 converts / extracts /
// transposes / caption-gather / g-col permutations. 13125 blocks x 256 thr.
// ---------------------------------------------------------------------------
__global__ __launch_bounds__(256)
void cvt_all_kernel(const float* __restrict__ feat, const float* __restrict__ enc_W,
                    const float* __restrict__ fc_W, const float* __restrict__ dec_W,
                    const float* __restrict__ W_ih, const float* __restrict__ W_hh,
                    const float* __restrict__ emb, const int* __restrict__ captions,
                    const float* __restrict__ b_ih, const float* __restrict__ b_hh,
                    ushort_t* __restrict__ featB, ushort_t* __restrict__ encWB,
                    ushort_t* __restrict__ fcWB, ushort_t* __restrict__ decWB,
                    ushort_t* __restrict__ WihCB, ushort_t* __restrict__ WihEB,
                    ushort_t* __restrict__ WhhT, ushort_t* __restrict__ XB,
                    float* __restrict__ bsum, float* __restrict__ zbuf)
{
    const int blk = blockIdx.x, tid = threadIdx.x;
    if (blk < 6272) {                       // featB flat
        size_t i = (size_t)blk * 2048 + tid * 8;
        float4 a = *(const float4*)&feat[i], b = *(const float4*)&feat[i + 4];
        u16x8 o; o[0]=bf_rne(a.x); o[1]=bf_rne(a.y); o[2]=bf_rne(a.z); o[3]=bf_rne(a.w);
        o[4]=bf_rne(b.x); o[5]=bf_rne(b.y); o[6]=bf_rne(b.z); o[7]=bf_rne(b.w);
        *(u16x8*)&featB[i] = o;
    } else if (blk < 6784) {                // encWB
        size_t i = (size_t)(blk - 6272) * 2048 + tid * 8;
        float4 a = *(const float4*)&enc_W[i], b = *(const float4*)&enc_W[i + 4];
        u16x8 o; o[0]=bf_rne(a.x); o[1]=bf_rne(a.y); o[2]=bf_rne(a.z); o[3]=bf_rne(a.w);
        o[4]=bf_rne(b.x); o[5]=bf_rne(b.y); o[6]=bf_rne(b.z); o[7]=bf_rne(b.w);
        *(u16x8*)&encWB[i] = o;
    } else if (blk < 9284) {                // fcWB
        size_t i = (size_t)(blk - 6784) * 2048 + tid * 8;
        float4 a = *(const float4*)&fc_W[i], b = *(const float4*)&fc_W[i + 4];
        u16x8 o; o[0]=bf_rne(a.x); o[1]=bf_rne(a.y); o[2]=bf_rne(a.z); o[3]=bf_rne(a.w);
        o[4]=bf_rne(b.x); o[5]=bf_rne(b.y); o[6]=bf_rne(b.z); o[7]=bf_rne(b.w);
        *(u16x8*)&fcWB[i] = o;
    } else if (blk < 9412) {                // decWB
        size_t i = (size_t)(blk - 9284) * 2048 + tid * 8;
        float4 a = *(const float4*)&dec_W[i], b = *(const float4*)&dec_W[i + 4];
        u16x8 o; o[0]=bf_rne(a.x); o[1]=bf_rne(a.y); o[2]=bf_rne(a.z); o[3]=bf_rne(a.w);
        o[4]=bf_rne(b.x); o[5]=bf_rne(b.y); o[6]=bf_rne(b.z); o[7]=bf_rne(b.w);
        *(u16x8*)&decWB[i] = o;
    } else if (blk < 11460) {               // WihCB[P(j)] = bf16(W_ih[j, 512:2560])
        int j = blk - 9412, f = tid * 8;
        int Pj = permc(j >> 3) * 8 + (j & 7);
        const float* s = &W_ih[(size_t)j * 2560 + 512 + f];
        float4 a = *(const float4*)&s[0], b = *(const float4*)&s[4];
        u16x8 o; o[0]=bf_rne(a.x); o[1]=bf_rne(a.y); o[2]=bf_rne(a.z); o[3]=bf_rne(a.w);
        o[4]=bf_rne(b.x); o[5]=bf_rne(b.y); o[6]=bf_rne(b.z); o[7]=bf_rne(b.w);
        *(u16x8*)&WihCB[(size_t)Pj * 2048 + f] = o;
    } else if (blk < 11972) {               // WihEB[P(j)] = bf16(W_ih[j, 0:512])
        size_t idx = (size_t)(blk - 11460) * 2048 + tid * 8;
        int j = (int)(idx >> 9), f = (int)(idx & 511);
        int Pj = permc(j >> 3) * 8 + (j & 7);
        const float* s = &W_ih[(size_t)j * 2560 + f];
        float4 a = *(const float4*)&s[0], b = *(const float4*)&s[4];
        u16x8 o; o[0]=bf_rne(a.x); o[1]=bf_rne(a.y); o[2]=bf_rne(a.z); o[3]=bf_rne(a.w);
        o[4]=bf_rne(b.x); o[5]=bf_rne(b.y); o[6]=bf_rne(b.z); o[7]=bf_rne(b.w);
        *(u16x8*)&WihEB[(size_t)Pj * 512 + f] = o;
    } else if (blk < 12484) {               // WhhT[k][P(j)] = bf16(W_hh[j][k])
        int k = blk - 11972, j0 = tid * 8;
        int nc = permc(tid);
        u16x8 o;
#pragma unroll
        for (int q = 0; q < 8; q++) o[q] = bf_rne(W_hh[(size_t)(j0 + q) * 512 + k]);
        *(u16x8*)&WhhT[(size_t)k * 2048 + nc * 8] = o;
    } else if (blk < 13124) {               // XB[m] = bf16(emb[captions]), m = t*32+b
        int m = blk - 12484;
        int tt = m >> 5, b = m & 31;
        int cap = captions[b * T_ + tt];
        int i = tid * 2;
        u16x2 o;
        o[0] = bf_rne(emb[(size_t)cap * 512 + i]);
        o[1] = bf_rne(emb[(size_t)cap * 512 + i + 1]);
        *(u16x2*)&XB[(size_t)m * 512 + i] = o;
    } else {                                // bsum (permuted) + zbuf
        int nc = permc(tid);
        int j0 = tid * 8;
#pragma unroll
        for (int q = 0; q < 8; q++) {
            bsum[nc * 8 + q] = b_ih[j0 + q] + b_hh[j0 + q];
            zbuf[j0 + q] = 0.f;
        }
    }
}

// ---------------------------------------------------------------------------
// bf16 MFMA GEMM: C[m,n] = A[m,:].B[n,:] + bias, A/B bf16 K-major.
// 128x128 tile, 4 waves, 4x4 of 16x16x32 MFMA per wave.
// Staging via global_load_lds width=16 (linear LDS layout, wave-uniform base).
// mode 0: bf16 store, bias[n].  mode 1: f32 store, crow=(m&31)*20+(m>>5).
// mode 2: f32 store plain.      mode 3: bf16 store, ROW bias[m].
// ---------------------------------------------------------------------------
__global__ __launch_bounds__(256)
void mfma_gemm_kernel(const ushort_t* __restrict__ A, const ushort_t* __restrict__ B,
                      const float* __restrict__ bias, ushort_t* __restrict__ Cb,
                      float* __restrict__ Cf, int K, int N, int mode)
{
    __shared__ ushort_t As[128][32];
    __shared__ ushort_t Bs[128][32];
    const int tid = threadIdx.x;
    const int m0 = blockIdx.x * 128, n0 = blockIdx.y * 128;
    const int wave = tid >> 6, lane = tid & 63;
    const int wm = (wave & 1) * 64, wn = (wave >> 1) * 64;
    const int lm = lane & 15, lk = (lane >> 4) * 8;

    f32x4 acc[4][4];
#pragma unroll
    for (int mt = 0; mt < 4; mt++)
#pragma unroll
        for (int nt = 0; nt < 4; nt++)
#pragma unroll
            for (int r = 0; r < 4; r++) acc[mt][nt][r] = 0.f;

    for (int k0 = 0; k0 < K; k0 += 32) {
#pragma unroll
        for (int i = 0; i < 2; i++) {
            int gi  = tid + i * 256;
            int row = gi >> 2;
            int gr  = (gi & 3) * 8;
            // LDS offset for this lane is gi*16B = wave-uniform base + lane*16B
            ushort_t* lbA = &As[0][0] + (size_t)(wave * 64 + i * 256) * 8;
            ushort_t* lbB = &Bs[0][0] + (size_t)(wave * 64 + i * 256) * 8;
            gl_lds16(&A[(size_t)(m0 + row) * K + k0 + gr], lbA);
            int brow = n0 + row; if (brow >= N) brow = N - 1;
            gl_lds16(&B[(size_t)brow * K + k0 + gr], lbB);
        }
        __syncthreads();
        bf16x8 af[4], bv[4];
#pragma unroll
        for (int mt = 0; mt < 4; mt++)
            af[mt] = *(const bf16x8*)&As[wm + mt * 16 + lm][lk];
#pragma unroll
        for (int nt = 0; nt < 4; nt++)
            bv[nt] = *(const bf16x8*)&Bs[wn + nt * 16 + lm][lk];
#pragma unroll
        for (int mt = 0; mt < 4; mt++)
#pragma unroll
            for (int nt = 0; nt < 4; nt++)
                acc[mt][nt] = __builtin_amdgcn_mfma_f32_16x16x32_bf16(
                    af[mt], bv[nt], acc[mt][nt], 0, 0, 0);
        __syncthreads();
    }

    const int rb = (lane >> 4) * 4;
#pragma unroll
    for (int nt = 0; nt < 4; nt++) {
        int n = n0 + wn + nt * 16 + lm;
        int nc = n < N ? n : N - 1;
        float bz = (mode == 3) ? 0.f : bias[nc];
#pragma unroll
        for (int mt = 0; mt < 4; mt++) {
            int mbase = m0 + wm + mt * 16 + rb;
#pragma unroll
            for (int r = 0; r < 4; r++) {
                int m = mbase + r;
                float v = acc[mt][nt][r] + ((mode == 3) ? bias[m] : bz);
                if (mode == 0 || mode == 3) {
                    Cb[(size_t)m * N + n] = bf_rne(v);
                } else if (n < N) {
                    int crow = (mode == 1) ? ((m & 31) * 20 + (m >> 5)) : m;
                    Cf[(size_t)crow * N + n] = v;
                }
            }
        }
    }
}

// ---------------------------------------------------------------------------
// Persistent 20-step decoder. 256 blocks = 32 groups x 8. Block (b,s):
//  - owns 256 permuted g-cols: Whh.h (WhhT streamed from L2, overlaps e-wait),
//    alpha.G (G in LDS, staged once), local pointwise (c in regs).
//  - owns attention a-slice [s*64,s*64+64): decW rows pinned in regs (64
//    VGPR), encPT slice pinned in LDS (25.6 KB).
// SYNC: data-as-flag. Every cross-block float is published as ONE relaxed
// agent-scope 64-bit atomic: (step_tag << 32) | f32bits. No counters, no
// release RMW, no separate poll->gather: consumer polls exactly the words it
// needs. Tag monotonicity + step dependencies prevent overwrite-before-read;
// single-word atomicity is placement-independent (G16-safe). Buffers are
// zeroed each replay so stale tags can't match.
// ---------------------------------------------------------------------------
__global__ __launch_bounds__(256, 1)
void persist_kernel(u64_t* __restrict__ hbufQ,          // [32][512] tagged h
                    ushort_t* __restrict__ hseqB,       // [21][32][512]
                    const ushort_t* __restrict__ encPT, // [512][6272] a-major
                    const ushort_t* __restrict__ decWB, // [512][512]
                    const float* __restrict__ dec_b,
                    const float* __restrict__ full_W,
                    const float* __restrict__ full_b,
                    const ushort_t* __restrict__ GB,    // [6272][2048] col-permuted
                    const ushort_t* __restrict__ WhhT,  // [512][2048] col-permuted
                    const float* __restrict__ xproj,    // [640][2048] col-permuted
                    u64_t* __restrict__ epartQ)         // [32][8][200] tagged eparts
{
    __shared__ ushort_t Gs[196][256];   // 100,352 B: this block's G col-slice
    __shared__ ushort_t ePs[64][200];   // 25,600 B: this block's encPT a-slice
    __shared__ float hsh[512];
    __shared__ float fws[512];
    __shared__ float dps64[64];
    __shared__ float dbias[64];
    __shared__ float es[200];
    __shared__ float al[200];
    __shared__ float sred[8][32][9];    // padded: conflict-free reduce scratch
    __shared__ float gsh[256];

    const int tid = threadIdx.x;
    const int b = blockIdx.x & 31;      // all 8 blocks of b -> same XCD
    const int s = blockIdx.x >> 5;
    u64_t* hbq = hbufQ + (size_t)b * 512;
    u64_t* epq = epartQ + (size_t)b * 1600;

    // ---- one-time: stage this block's (contiguous, permuted) G slice
    {
        const int r0 = tid >> 5, c = (tid & 31) * 8;
        for (int i = 0; i < 25; i++) {
            int r = i * 8 + r0;
            if (r < 196)
                *(u16x8*)&Gs[r][c] =
                    *(const u16x8*)&GB[((size_t)(b * P_ + r)) * 2048 + s * 256 + c];
        }
    }
    // ---- one-time: stage encPT a-slice (64 rows x 196 u16, as 98 u16x2)
    for (int it = 0; it < 25; it++) {
        int idx = it * 256 + tid;
        if (idx < 6272) {
            int a = idx / 98, pp = idx - a * 98;
            *(u16x2*)&ePs[a][pp * 2] =
                *(const u16x2*)&encPT[(size_t)(s * 64 + a) * 6272 + b * P_ + pp * 2];
        }
    }
    if (tid < 128)
        *(float4*)&fws[tid * 4] = *(const float4*)&full_W[tid * 4];
    if (tid < 64)
        dbias[tid] = dec_b[s * 64 + tid];

    const int lane = tid & 63, wave = tid >> 6;
    const int g16 = lane >> 4, gl = lane & 15;
    const int kg = tid >> 5, cg = tid & 31;
    const float fb0 = full_b[0];
    float c_reg = 0.f;

    // ---- one-time: pin this thread's decW dps-slice in registers (64 VGPR)
    u16x8 dreg[16];
#pragma unroll
    for (int q = 0; q < 4; q++) {
        int a = wave * 16 + q * 4 + g16;
        const ushort_t* wr = decWB + (size_t)(s * 64 + a) * 512;
#pragma unroll
        for (int jj = 0; jj < 4; jj++)
            dreg[q * 4 + jj] = *(const u16x8*)&wr[jj * 128 + gl * 8];
    }

    for (int t = 0; t < T_; t++) {
        // ---- prefetch xproj for this step (independent of h; hides under poll)
        float gx = xproj[(size_t)(t * 32 + b) * 2048 + s * 256 + tid];

        // ---- acquire h(t): poll own 2 tagged words (tag == t)
        if (t == 0) {
            hsh[tid * 2] = 0.f; hsh[tid * 2 + 1] = 0.f;
        } else {
            const unsigned tag = (unsigned)t;
            u64_t w0 = 0, w1 = 0;
            bool g0 = false, g1 = false;
            while (!(g0 && g1)) {
                if (!g0) w0 = __hip_atomic_load(&hbq[tid * 2],
                                __ATOMIC_RELAXED, __HIP_MEMORY_SCOPE_AGENT);
                if (!g1) w1 = __hip_atomic_load(&hbq[tid * 2 + 1],
                                __ATOMIC_RELAXED, __HIP_MEMORY_SCOPE_AGENT);
                g0 = g0 || ((unsigned)(w0 >> 32) == tag);
                g1 = g1 || ((unsigned)(w1 >> 32) == tag);
                if (!(g0 && g1)) __builtin_amdgcn_s_sleep(1);
            }
            hsh[tid * 2]     = u2f((unsigned)w0);
            hsh[tid * 2 + 1] = u2f((unsigned)w1);
        }
        __syncthreads();

        // ---- dps for own a-slice from REGISTERS: a_glob = s*64 + a
        if (t == 0) {
            if (tid < 64) dps64[tid] = dbias[tid];
        } else {
#pragma unroll
            for (int q = 0; q < 4; q++) {
                int a = wave * 16 + q * 4 + g16;        // [0,64)
                float sacc = 0.f;
#pragma unroll
                for (int jj = 0; jj < 4; jj++) {
                    u16x8 wv = dreg[q * 4 + jj];
                    float4 h0 = *(float4*)&hsh[jj * 128 + gl * 8];
                    float4 h1 = *(float4*)&hsh[jj * 128 + gl * 8 + 4];
                    sacc += b2f(wv[0]) * h0.x + b2f(wv[1]) * h0.y
                          + b2f(wv[2]) * h0.z + b2f(wv[3]) * h0.w
                          + b2f(wv[4]) * h1.x + b2f(wv[5]) * h1.y
                          + b2f(wv[6]) * h1.z + b2f(wv[7]) * h1.w;
                }
                sacc += __shfl_xor(sacc, 1, 64); sacc += __shfl_xor(sacc, 2, 64);
                sacc += __shfl_xor(sacc, 4, 64); sacc += __shfl_xor(sacc, 8, 64);
                if (gl == 0) dps64[a] = sacc + dbias[a];
            }
        }
        __syncthreads();

        // ---- partial energies over own 64 a's (LDS) -> tagged publish
        if (tid < 196) {
            float e = 0.f;
#pragma unroll 8
            for (int a = 0; a < 64; a++)
                e += fmaxf(b2f(ePs[a][tid]) + dps64[a], 0.f) * fws[s * 64 + a];
            u64_t w = ((u64_t)(unsigned)(t + 1) << 32) | (u64_t)f2u(e);
            __hip_atomic_store(&epq[s * 200 + tid], w,
                               __ATOMIC_RELAXED, __HIP_MEMORY_SCOPE_AGENT);
        }

        // ---- Whh^T.h slice from L2 (latency-tolerant, overlaps the e-wait)
        {
            float wa[8] = {0.f,0.f,0.f,0.f,0.f,0.f,0.f,0.f};
            const ushort_t* wp = WhhT + (size_t)(kg * 64) * 2048 + s * 256 + cg * 8;
#pragma unroll 8
            for (int kk = 0; kk < 64; kk++) {
                u16x8 wv = *(const u16x8*)&wp[(size_t)kk * 2048];
                float hv = hsh[kg * 64 + kk];
#pragma unroll
                for (int q = 0; q < 8; q++) wa[q] += b2f(wv[q]) * hv;
            }
#pragma unroll
            for (int q = 0; q < 8; q++) sred[kg][cg][q] = wa[q];
        }
        __syncthreads();
        float g = gx;
#pragma unroll
        for (int k2 = 0; k2 < 8; k2++) g += sred[k2][tid >> 3][tid & 7];

        // ---- gather 8 tagged eparts (poll all outstanding in parallel)
        if (tid < 196) {
            const unsigned tag = (unsigned)(t + 1);
            u64_t wv[8];
            unsigned ok = 0;
            while (ok != 0xffu) {
#pragma unroll
                for (int s2 = 0; s2 < 8; s2++)
                    if (!(ok & (1u << s2)))
                        wv[s2] = __hip_atomic_load(&epq[s2 * 200 + tid],
                                     __ATOMIC_RELAXED, __HIP_MEMORY_SCOPE_AGENT);
#pragma unroll
                for (int s2 = 0; s2 < 8; s2++)
                    if (!(ok & (1u << s2)) && ((unsigned)(wv[s2] >> 32) == tag))
                        ok |= 1u << s2;
                if (ok != 0xffu) __builtin_amdgcn_s_sleep(1);
            }
            float e = fb0;
#pragma unroll
            for (int s2 = 0; s2 < 8; s2++) e += u2f((unsigned)wv[s2]);
            es[tid] = e;
        }
        __syncthreads();
        if (tid < 64) {
            float v[4]; int pv[4]; int n = 0;
            for (int q = 0; q < 4; q++) {
                int p = tid + 64 * q;
                if (p < P_) { pv[n] = p; v[n] = es[p]; n++; }
            }
            float m = -1e30f;
            for (int q = 0; q < n; q++) m = fmaxf(m, v[q]);
#pragma unroll
            for (int off = 32; off > 0; off >>= 1) m = fmaxf(m, __shfl_xor(m, off, 64));
            float ssum = 0.f;
            for (int q = 0; q < n; q++) { v[q] = expf(v[q] - m); ssum += v[q]; }
#pragma unroll
            for (int off = 32; off > 0; off >>= 1) ssum += __shfl_xor(ssum, off, 64);
            float rinv = 1.f / ssum;
            for (int q = 0; q < n; q++) al[pv[q]] = v[q] * rinv;
        }
        __syncthreads();

        // ---- alpha.G slice (from LDS)
        {
            int p0 = (kg < 4) ? kg * 25 : 100 + (kg - 4) * 24;
            int np = (kg < 4) ? 25 : 24;
            float pa[8] = {0.f,0.f,0.f,0.f,0.f,0.f,0.f,0.f};
#pragma unroll 4
            for (int i = 0; i < np; i++) {
                int p = p0 + i;
                float av = al[p];
                u16x8 gv = *(const u16x8*)&Gs[p][cg * 8];
#pragma unroll
                for (int q = 0; q < 8; q++) pa[q] += b2f(gv[q]) * av;
            }
#pragma unroll
            for (int q = 0; q < 8; q++) sred[kg][cg][q] = pa[q];
        }
        __syncthreads();
#pragma unroll
        for (int k2 = 0; k2 < 8; k2++) g += sred[k2][tid >> 3][tid & 7];
        gsh[tid] = g;
        __syncthreads();

        // ---- block-local pointwise LSTM; publish tagged h(t+1)
        if (tid < 64) {
            int ri = tid >> 3, e = tid & 7;
            float gi = gsh[ri * 32 + e];
            float gf = gsh[ri * 32 + 8 + e];
            float gg = gsh[ri * 32 + 16 + e];
            float go = gsh[ri * 32 + 24 + e];
            float ig = 1.f / (1.f + expf(-gi));
            float fg = 1.f / (1.f + expf(-gf));
            float g_ = tanhf(gg);
            float og = 1.f / (1.f + expf(-go));
            c_reg = fg * c_reg + ig * g_;
            float hn = og * tanhf(c_reg);
            int u = 8 * s + 64 * ri + e;
            u64_t w = ((u64_t)(unsigned)(t + 1) << 32) | (u64_t)f2u(hn);
            __hip_atomic_store(&hbq[u], w,
                               __ATOMIC_RELAXED, __HIP_MEMORY_SCOPE_AGENT);
            hseqB[(size_t)(t + 1) * 16384 + b * 512 + u] = bf_rne(hn);
        }
        __syncthreads();
    }
}

// ---------------------------------------------------------------------------
extern "C" void kernel_launch(void* const* d_in, const int* in_sizes, int n_in,
                              void* d_out, int out_size, void* d_ws, size_t ws_size,
                              hipStream_t stream)
{
    (void)in_sizes; (void)n_in; (void)out_size; (void)ws_size;
    const float* feat   = (const float*)d_in[0];
    const int*   caps   = (const int*)  d_in[1];
    const float* emb    = (const float*)d_in[2];
    const float* W_ih   = (const float*)d_in[3];
    const float* b_ih   = (const float*)d_in[4];
    const float* W_hh   = (const float*)d_in[5];
    const float* b_hh   = (const float*)d_in[6];
    const float* fc_W   = (const float*)d_in[7];
    const float* fc_b   = (const float*)d_in[8];
    const float* enc_W  = (const float*)d_in[9];
    const float* enc_b  = (const float*)d_in[10];
    const float* dec_W  = (const float*)d_in[11];
    const float* dec_b  = (const float*)d_in[12];
    const float* full_W = (const float*)d_in[13];
    const float* full_b = (const float*)d_in[14];
    float* out = (float*)d_out;

    // workspace carve (~90 MB), 128B-aligned chunks
    char* w = (char*)d_ws;
    ushort_t* featB = (ushort_t*)w;              w += 25690112;  // [6272][2048]
    ushort_t* encWB = (ushort_t*)w;              w += 2097152;   // [512][2048]
    ushort_t* fcWB  = (ushort_t*)w;              w += 10240000;  // [10000][512]
    ushort_t* decWB = (ushort_t*)w;              w += 524288;    // [512][512]
    ushort_t* WihCB = (ushort_t*)w;              w += 8388608;   // [2048][2048] (rows permuted)
    ushort_t* WihEB = (ushort_t*)w;              w += 2097152;   // [2048][512]  (rows permuted)
    ushort_t* WhhT  = (ushort_t*)w;              w += 2097152;   // [512][2048]  (cols permuted)
    ushort_t* XB    = (ushort_t*)w;              w += 655360;    // [640][512]
    ushort_t* encPT = (ushort_t*)w;              w += 6422528;   // [512][6272] a-major
    ushort_t* GB    = (ushort_t*)w;              w += 25690112;  // [6272][2048] (cols permuted)
    float*    xproj = (float*)w;                 w += 5242880;   // [640][2048]  (cols permuted)
    float*    bsum  = (float*)w;                 w += 8192;      // [2048] (permuted)
    float*    zbuf  = (float*)w;                 w += 8192;      // [2048]
    ushort_t* hseqB = (ushort_t*)w;              w += 688128;    // [21][32][512]
    u64_t*    hbufQ = (u64_t*)w;                 w += 131072;    // [32][512] tagged
    u64_t*    epartQ= (u64_t*)w;                 w += 409600;    // [32][8][200] tagged

    // zero tagged sync buffers (contiguous; ws re-poisoned each replay)
    hipMemsetAsync(hbufQ, 0, 131072 + 409600, stream);

    // one-time converts / extracts / transposes / gathers / permutes (1 node)
    cvt_all_kernel<<<13125, 256, 0, stream>>>(
        feat, enc_W, fc_W, dec_W, W_ih, W_hh, emb, caps, b_ih, b_hh,
        featB, encWB, fcWB, decWB, WihCB, WihEB, WhhT, XB, bsum, zbuf);

    // enc_proj TRANSPOSED: [512,2048]x[6272,2048]^T -> encPT[a][b*196+p] bf16
    // (row bias enc_b[a] via mode 3)
    mfma_gemm_kernel<<<dim3(4, 49), 256, 0, stream>>>(
        encWB, featB, enc_b, encPT, nullptr, 2048, 6272, 3);

    // G = feat . W_ihC^T (rows of WihCB permuted -> GB cols permuted) bf16
    mfma_gemm_kernel<<<dim3(49, 16), 256, 0, stream>>>(
        featB, WihCB, zbuf, GB, nullptr, 2048, 2048, 0);

    // xproj = X . W_ihE^T + bsum (cols permuted to match)
    mfma_gemm_kernel<<<dim3(5, 16), 256, 0, stream>>>(
        XB, WihEB, bsum, nullptr, xproj, 512, 2048, 2);

    // persistent 20-step recurrent loop: data-as-flag sync, zero counters
    persist_kernel<<<NBLK, 256, 0, stream>>>(
        hbufQ, hseqB, encPT, decWB, dec_b, full_W, full_b,
        GB, WhhT, xproj, epartQ);

    // batched vocab FC: [640,512]x[10000,512]^T -> out (f32, remapped rows)
    mfma_gemm_kernel<<<dim3(5, 79), 256, 0, stream>>>(
        hseqB + 16384, fcWB, fc_b, nullptr, out, 512, V_, 1);
}

// Round 7
// 712.835 us; speedup vs baseline: 1.2315x; 1.0293x over previous
//
#include <hip/hip_runtime.h>
#include <math.h>

#define B_   32
#define P_   196
#define F_   2048
#define E_   512
#define H_   512
#define V_   10000
#define T_   20
#define GSZ  8            // blocks per batch-element group
#define NBLK (B_ * GSZ)   // 256 persistent blocks = 1 per CU (LDS-limited)

typedef unsigned short ushort_t;
typedef unsigned long long u64_t;
typedef ushort_t u16x8 __attribute__((ext_vector_type(8)));
typedef ushort_t u16x2 __attribute__((ext_vector_type(2)));
typedef short    bf16x8 __attribute__((ext_vector_type(8)));
typedef float    f32x4  __attribute__((ext_vector_type(4)));

__device__ __forceinline__ ushort_t bf_rne(float x) {
    union { float f; unsigned u; } v; v.f = x;
    unsigned r = v.u + 0x7FFFu + ((v.u >> 16) & 1u);
    return (ushort_t)(r >> 16);
}
__device__ __forceinline__ float b2f(ushort_t u) {
    union { unsigned u; float f; } v; v.u = ((unsigned)u) << 16;
    return v.f;
}
__device__ __forceinline__ unsigned f2u(float f) {
    union { float f; unsigned u; } v; v.f = f; return v.u;
}
__device__ __forceinline__ float u2f(unsigned u) {
    union { unsigned u; float f; } v; v.u = u; return v.f;
}

// async global->LDS, 16B per lane. LDS dest is wave-uniform base + lane*16.
__device__ __forceinline__ void gl_lds16(const ushort_t* g, ushort_t* l) {
    __builtin_amdgcn_global_load_lds(
        (const __attribute__((address_space(1))) void*)g,
        (__attribute__((address_space(3))) void*)l, 16, 0, 0);
}

// Column permutation: g-col j -> P(j) = s_own*256 + ri*32 + gi*8 + e.
// chunk=j>>3, gi=chunk>>6 (gate), r=chunk&63, owner=r&7, ri=r>>3, e=j&7.
// Gate stride 512 = 64 chunks -> all 4 gates of one hidden unit share owner.
__device__ __forceinline__ int permc(int chunk) {   // chunk in [0,256) -> new chunk
    int gi = chunk >> 6, r = chunk & 63;
    return (r & 7) * 32 + (r >> 3) * 4 + gi;
}

// ---------------------------------------------------------------------------
// One-time conversion mega-kernel (1 node): bf16 converts / extracts /
// transposes / caption-gather / g-col permutations. 13125 blocks x 256 thr.
// ---------------------------------------------------------------------------
__global__ __launch_bounds__(256)
void cvt_all_kernel(const float* __restrict__ feat, const float* __restrict__ enc_W,
                    const float* __restrict__ fc_W, const float* __restrict__ dec_W,
                    const float* __restrict__ W_ih, const float* __restrict__ W_hh,
                    const float* __restrict__ emb, const int* __restrict__ captions,
                    const float* __restrict__ b_ih, const float* __restrict__ b_hh,
                    ushort_t* __restrict__ featB, ushort_t* __restrict__ encWB,
                    ushort_t* __restrict__ fcWB, ushort_t* __restrict__ decWB,
                    ushort_t* __restrict__ WihCB, ushort_t* __restrict__ WihEB,
                    ushort_t* __restrict__ WhhT, ushort_t* __restrict__ XB,
                    float* __restrict__ bsum, float* __restrict__ zbuf)
{
    const int blk = blockIdx.x, tid = threadIdx.x;
    if (blk < 6272) {                       // featB flat
        size_t i = (size_t)blk * 2048 + tid * 8;
        float4 a = *(const float4*)&feat[i], b = *(const float4*)&feat[i + 4];
        u16x8 o; o[0]=bf_rne(a.x); o[1]=bf_rne(a.y); o[2]=bf_rne(a.z); o[3]=bf_rne(a.w);
        o[4]=bf_rne(b.x); o[5]=bf_rne(b.y); o[6]=bf_rne(b.z); o[7]=bf_rne(b.w);
        *(u16x8*)&featB[i] = o;
    } else if (blk < 6784) {                // encWB
        size_t i = (size_t)(blk - 6272) * 2048 + tid * 8;
        float4 a = *(const float4*)&enc_W[i], b = *(const float4*)&enc_W[i + 4];
        u16x8 o; o[0]=bf_rne(a.x); o[1]=bf_rne(a.y); o[2]=bf_rne(a.z); o[3]=bf_rne(a.w);
        o[4]=bf_rne(b.x); o[5]=bf_rne(b.y); o[6]=bf_rne(b.z); o[7]=bf_rne(b.w);
        *(u16x8*)&encWB[i] = o;
    } else if (blk < 9284) {                // fcWB
        size_t i = (size_t)(blk - 6784) * 2048 + tid * 8;
        float4 a = *(const float4*)&fc_W[i], b = *(const float4*)&fc_W[i + 4];
        u16x8 o; o[0]=bf_rne(a.x); o[1]=bf_rne(a.y); o[2]=bf_rne(a.z); o[3]=bf_rne(a.w);
        o[4]=bf_rne(b.x); o[5]=bf_rne(b.y); o[6]=bf_rne(b.z); o[7]=bf_rne(b.w);
        *(u16x8*)&fcWB[i] = o;
    } else if (blk < 9412) {                // decWB
        size_t i = (size_t)(blk - 9284) * 2048 + tid * 8;
        float4 a = *(const float4*)&dec_W[i], b = *(const float4*)&dec_W[i + 4];
        u16x8 o; o[0]=bf_rne(a.x); o[1]=bf_rne(a.y); o[2]=bf_rne(a.z); o[3]=bf_rne(a.w);
        o[4]=bf_rne(b.x); o[5]=bf_rne(b.y); o[6]=bf_rne(b.z); o[7]=bf_rne(b.w);
        *(u16x8*)&decWB[i] = o;
    } else if (blk < 11460) {               // WihCB[P(j)] = bf16(W_ih[j, 512:2560])
        int j = blk - 9412, f = tid * 8;
        int Pj = permc(j >> 3) * 8 + (j & 7);
        const float* s = &W_ih[(size_t)j * 2560 + 512 + f];
        float4 a = *(const float4*)&s[0], b = *(const float4*)&s[4];
        u16x8 o; o[0]=bf_rne(a.x); o[1]=bf_rne(a.y); o[2]=bf_rne(a.z); o[3]=bf_rne(a.w);
        o[4]=bf_rne(b.x); o[5]=bf_rne(b.y); o[6]=bf_rne(b.z); o[7]=bf_rne(b.w);
        *(u16x8*)&WihCB[(size_t)Pj * 2048 + f] = o;
    } else if (blk < 11972) {               // WihEB[P(j)] = bf16(W_ih[j, 0:512])
        size_t idx = (size_t)(blk - 11460) * 2048 + tid * 8;
        int j = (int)(idx >> 9), f = (int)(idx & 511);
        int Pj = permc(j >> 3) * 8 + (j & 7);
        const float* s = &W_ih[(size_t)j * 2560 + f];
        float4 a = *(const float4*)&s[0], b = *(const float4*)&s[4];
        u16x8 o; o[0]=bf_rne(a.x); o[1]=bf_rne(a.y); o[2]=bf_rne(a.z); o[3]=bf_rne(a.w);
        o[4]=bf_rne(b.x); o[5]=bf_rne(b.y); o[6]=bf_rne(b.z); o[7]=bf_rne(b.w);
        *(u16x8*)&WihEB[(size_t)Pj * 512 + f] = o;
    } else if (blk < 12484) {               // WhhT[k][P(j)] = bf16(W_hh[j][k])
        int k = blk - 11972, j0 = tid * 8;
        int nc = permc(tid);
        u16x8 o;
#pragma unroll
        for (int q = 0; q < 8; q++) o[q] = bf_rne(W_hh[(size_t)(j0 + q) * 512 + k]);
        *(u16x8*)&WhhT[(size_t)k * 2048 + nc * 8] = o;
    } else if (blk < 13124) {               // XB[m] = bf16(emb[captions]), m = t*32+b
        int m = blk - 12484;
        int tt = m >> 5, b = m & 31;
        int cap = captions[b * T_ + tt];
        int i = tid * 2;
        u16x2 o;
        o[0] = bf_rne(emb[(size_t)cap * 512 + i]);
        o[1] = bf_rne(emb[(size_t)cap * 512 + i + 1]);
        *(u16x2*)&XB[(size_t)m * 512 + i] = o;
    } else {                                // bsum (permuted) + zbuf
        int nc = permc(tid);
        int j0 = tid * 8;
#pragma unroll
        for (int q = 0; q < 8; q++) {
            bsum[nc * 8 + q] = b_ih[j0 + q] + b_hh[j0 + q];
            zbuf[j0 + q] = 0.f;
        }
    }
}

// ---------------------------------------------------------------------------
// bf16 MFMA GEMM: C[m,n] = A[m,:].B[n,:] + bias, A/B bf16 K-major.
// 128x128 tile, 4 waves, 4x4 of 16x16x32 MFMA per wave.
// Staging via global_load_lds width=16 (linear LDS layout, wave-uniform base).
// mode 0: bf16 store, bias[n].  mode 1: f32 store, crow=(m&31)*20+(m>>5).
// mode 2: f32 store plain.      mode 3: bf16 store, ROW bias[m].
// ---------------------------------------------------------------------------
__global__ __launch_bounds__(256)
void mfma_gemm_kernel(const ushort_t* __restrict__ A, const ushort_t* __restrict__ B,
                      const float* __restrict__ bias, ushort_t* __restrict__ Cb,
                      float* __restrict__ Cf, int K, int N, int mode)
{
    __shared__ ushort_t As[128][32];
    __shared__ ushort_t Bs[128][32];
    const int tid = threadIdx.x;
    const int m0 = blockIdx.x * 128, n0 = blockIdx.y * 128;
    const int wave = tid >> 6, lane = tid & 63;
    const int wm = (wave & 1) * 64, wn = (wave >> 1) * 64;
    const int lm = lane & 15, lk = (lane >> 4) * 8;

    f32x4 acc[4][4];
#pragma unroll
    for (int mt = 0; mt < 4; mt++)
#pragma unroll
        for (int nt = 0; nt < 4; nt++)
#pragma unroll
            for (int r = 0; r < 4; r++) acc[mt][nt][r] = 0.f;

    for (int k0 = 0; k0 < K; k0 += 32) {
#pragma unroll
        for (int i = 0; i < 2; i++) {
            int gi  = tid + i * 256;
            int row = gi >> 2;
            int gr  = (gi & 3) * 8;
            // LDS offset for this lane is gi*16B = wave-uniform base + lane*16B
            ushort_t* lbA = &As[0][0] + (size_t)(wave * 64 + i * 256) * 8;
            ushort_t* lbB = &Bs[0][0] + (size_t)(wave * 64 + i * 256) * 8;
            gl_lds16(&A[(size_t)(m0 + row) * K + k0 + gr], lbA);
            int brow = n0 + row; if (brow >= N) brow = N - 1;
            gl_lds16(&B[(size_t)brow * K + k0 + gr], lbB);
        }
        __syncthreads();
        bf16x8 af[4], bv[4];
#pragma unroll
        for (int mt = 0; mt < 4; mt++)
            af[mt] = *(const bf16x8*)&As[wm + mt * 16 + lm][lk];
#pragma unroll
        for (int nt = 0; nt < 4; nt++)
            bv[nt] = *(const bf16x8*)&Bs[wn + nt * 16 + lm][lk];
#pragma unroll
        for (int mt = 0; mt < 4; mt++)
#pragma unroll
            for (int nt = 0; nt < 4; nt++)
                acc[mt][nt] = __builtin_amdgcn_mfma_f32_16x16x32_bf16(
                    af[mt], bv[nt], acc[mt][nt], 0, 0, 0);
        __syncthreads();
    }

    const int rb = (lane >> 4) * 4;
#pragma unroll
    for (int nt = 0; nt < 4; nt++) {
        int n = n0 + wn + nt * 16 + lm;
        int nc = n < N ? n : N - 1;
        float bz = (mode == 3) ? 0.f : bias[nc];
#pragma unroll
        for (int mt = 0; mt < 4; mt++) {
            int mbase = m0 + wm + mt * 16 + rb;
#pragma unroll
            for (int r = 0; r < 4; r++) {
                int m = mbase + r;
                float v = acc[mt][nt][r] + ((mode == 3) ? bias[m] : bz);
                if (mode == 0 || mode == 3) {
                    Cb[(size_t)m * N + n] = bf_rne(v);
                } else if (n < N) {
                    int crow = (mode == 1) ? ((m & 31) * 20 + (m >> 5)) : m;
                    Cf[(size_t)crow * N + n] = v;
                }
            }
        }
    }
}

// ---------------------------------------------------------------------------
// 256x256-tile bf16 MFMA GEMM (for the big G matmul). 512 threads, 8 waves
// (2 m x 4 n), each wave 128x64 = 8x4 of 16x16x32 MFMA. Halves operand
// re-reads vs 128-tile (A x8, B x25 at M=6272,N=2048) and raises the
// MFMA:ds_read ratio (32:12 vs 16:8 per K-step). bf16 store, bias[n],
// A-row clamp + m-store guard for M not divisible by 256.
// ---------------------------------------------------------------------------
__global__ __launch_bounds__(512)
void mfma_gemm256_kernel(const ushort_t* __restrict__ A, const ushort_t* __restrict__ B,
                         const float* __restrict__ bias, ushort_t* __restrict__ Cb,
                         int M, int K, int N)
{
    __shared__ ushort_t As[256][32];
    __shared__ ushort_t Bs[256][32];
    const int tid = threadIdx.x;
    const int m0 = blockIdx.x * 256, n0 = blockIdx.y * 256;
    const int wave = tid >> 6, lane = tid & 63;
    const int wm = (wave & 1) * 128, wn = (wave >> 1) * 64;
    const int lm = lane & 15, lk = (lane >> 4) * 8;

    f32x4 acc[8][4];
#pragma unroll
    for (int mt = 0; mt < 8; mt++)
#pragma unroll
        for (int nt = 0; nt < 4; nt++)
#pragma unroll
            for (int r = 0; r < 4; r++) acc[mt][nt][r] = 0.f;

    for (int k0 = 0; k0 < K; k0 += 32) {
#pragma unroll
        for (int i = 0; i < 2; i++) {
            int gi  = tid + i * 512;
            int row = gi >> 2;
            int gr  = (gi & 3) * 8;
            ushort_t* lbA = &As[0][0] + (size_t)(wave * 64 + i * 512) * 8;
            ushort_t* lbB = &Bs[0][0] + (size_t)(wave * 64 + i * 512) * 8;
            int arow = m0 + row; if (arow >= M) arow = M - 1;
            gl_lds16(&A[(size_t)arow * K + k0 + gr], lbA);
            int brow = n0 + row; if (brow >= N) brow = N - 1;
            gl_lds16(&B[(size_t)brow * K + k0 + gr], lbB);
        }
        __syncthreads();
        bf16x8 af[8], bv[4];
#pragma unroll
        for (int mt = 0; mt < 8; mt++)
            af[mt] = *(const bf16x8*)&As[wm + mt * 16 + lm][lk];
#pragma unroll
        for (int nt = 0; nt < 4; nt++)
            bv[nt] = *(const bf16x8*)&Bs[wn + nt * 16 + lm][lk];
#pragma unroll
        for (int mt = 0; mt < 8; mt++)
#pragma unroll
            for (int nt = 0; nt < 4; nt++)
                acc[mt][nt] = __builtin_amdgcn_mfma_f32_16x16x32_bf16(
                    af[mt], bv[nt], acc[mt][nt], 0, 0, 0);
        __syncthreads();
    }

    const int rb = (lane >> 4) * 4;
#pragma unroll
    for (int nt = 0; nt < 4; nt++) {
        int n = n0 + wn + nt * 16 + lm;
        int nc = n < N ? n : N - 1;
        float bz = bias[nc];
#pragma unroll
        for (int mt = 0; mt < 8; mt++) {
            int mbase = m0 + wm + mt * 16 + rb;
#pragma unroll
            for (int r = 0; r < 4; r++) {
                int m = mbase + r;
                if (m < M && n < N)
                    Cb[(size_t)m * N + n] = bf_rne(acc[mt][nt][r] + bz);
            }
        }
    }
}

// ---------------------------------------------------------------------------
// Persistent 20-step decoder. 256 blocks = 32 groups x 8. Block (b,s):
//  - owns 256 permuted g-cols: Whh.h (WhhT streamed from L2, overlaps e-wait),
//    alpha.G (G in LDS, staged once), local pointwise (c in regs).
//  - owns attention a-slice [s*64,s*64+64): decW rows pinned in regs (64
//    VGPR), encPT slice pinned in LDS (25.6 KB).
// SYNC: data-as-flag. Every cross-block float is published as ONE relaxed
// agent-scope 64-bit atomic: (step_tag << 32) | f32bits. No counters, no
// release RMW, no separate poll->gather: consumer polls exactly the words it
// needs. Tag monotonicity + step dependencies prevent overwrite-before-read;
// single-word atomicity is placement-independent (G16-safe). Buffers are
// zeroed each replay so stale tags can't match.
// ---------------------------------------------------------------------------
__global__ __launch_bounds__(256, 1)
void persist_kernel(u64_t* __restrict__ hbufQ,          // [32][512] tagged h
                    ushort_t* __restrict__ hseqB,       // [21][32][512]
                    const ushort_t* __restrict__ encPT, // [512][6272] a-major
                    const ushort_t* __restrict__ decWB, // [512][512]
                    const float* __restrict__ dec_b,
                    const float* __restrict__ full_W,
                    const float* __restrict__ full_b,
                    const ushort_t* __restrict__ GB,    // [6272][2048] col-permuted
                    const ushort_t* __restrict__ WhhT,  // [512][2048] col-permuted
                    const float* __restrict__ xproj,    // [640][2048] col-permuted
                    u64_t* __restrict__ epartQ)         // [32][8][200] tagged eparts
{
    __shared__ ushort_t Gs[196][256];   // 100,352 B: this block's G col-slice
    __shared__ ushort_t ePs[64][200];   // 25,600 B: this block's encPT a-slice
    __shared__ float hsh[512];
    __shared__ float fws[512];
    __shared__ float dps64[64];
    __shared__ float dbias[64];
    __shared__ float es[200];
    __shared__ float al[200];
    __shared__ float sred[8][32][9];    // padded: conflict-free reduce scratch
    __shared__ float gsh[256];

    const int tid = threadIdx.x;
    const int b = blockIdx.x & 31;      // all 8 blocks of b -> same XCD
    const int s = blockIdx.x >> 5;
    u64_t* hbq = hbufQ + (size_t)b * 512;
    u64_t* epq = epartQ + (size_t)b * 1600;

    // ---- one-time: stage this block's (contiguous, permuted) G slice
    {
        const int r0 = tid >> 5, c = (tid & 31) * 8;
        for (int i = 0; i < 25; i++) {
            int r = i * 8 + r0;
            if (r < 196)
                *(u16x8*)&Gs[r][c] =
                    *(const u16x8*)&GB[((size_t)(b * P_ + r)) * 2048 + s * 256 + c];
        }
    }
    // ---- one-time: stage encPT a-slice (64 rows x 196 u16, as 98 u16x2)
    for (int it = 0; it < 25; it++) {
        int idx = it * 256 + tid;
        if (idx < 6272) {
            int a = idx / 98, pp = idx - a * 98;
            *(u16x2*)&ePs[a][pp * 2] =
                *(const u16x2*)&encPT[(size_t)(s * 64 + a) * 6272 + b * P_ + pp * 2];
        }
    }
    if (tid < 128)
        *(float4*)&fws[tid * 4] = *(const float4*)&full_W[tid * 4];
    if (tid < 64)
        dbias[tid] = dec_b[s * 64 + tid];

    const int lane = tid & 63, wave = tid >> 6;
    const int g16 = lane >> 4, gl = lane & 15;
    const int kg = tid >> 5, cg = tid & 31;
    const float fb0 = full_b[0];
    float c_reg = 0.f;

    // ---- one-time: pin this thread's decW dps-slice in registers (64 VGPR)
    u16x8 dreg[16];
#pragma unroll
    for (int q = 0; q < 4; q++) {
        int a = wave * 16 + q * 4 + g16;
        const ushort_t* wr = decWB + (size_t)(s * 64 + a) * 512;
#pragma unroll
        for (int jj = 0; jj < 4; jj++)
            dreg[q * 4 + jj] = *(const u16x8*)&wr[jj * 128 + gl * 8];
    }

    for (int t = 0; t < T_; t++) {
        // ---- prefetch xproj for this step (independent of h; hides under poll)
        float gx = xproj[(size_t)(t * 32 + b) * 2048 + s * 256 + tid];

        // ---- acquire h(t): poll own 2 tagged words (tag == t)
        if (t == 0) {
            hsh[tid * 2] = 0.f; hsh[tid * 2 + 1] = 0.f;
        } else {
            const unsigned tag = (unsigned)t;
            u64_t w0 = 0, w1 = 0;
            bool g0 = false, g1 = false;
            while (!(g0 && g1)) {
                if (!g0) w0 = __hip_atomic_load(&hbq[tid * 2],
                                __ATOMIC_RELAXED, __HIP_MEMORY_SCOPE_AGENT);
                if (!g1) w1 = __hip_atomic_load(&hbq[tid * 2 + 1],
                                __ATOMIC_RELAXED, __HIP_MEMORY_SCOPE_AGENT);
                g0 = g0 || ((unsigned)(w0 >> 32) == tag);
                g1 = g1 || ((unsigned)(w1 >> 32) == tag);
                if (!(g0 && g1)) __builtin_amdgcn_s_sleep(1);
            }
            hsh[tid * 2]     = u2f((unsigned)w0);
            hsh[tid * 2 + 1] = u2f((unsigned)w1);
        }
        __syncthreads();

        // ---- dps for own a-slice from REGISTERS: a_glob = s*64 + a
        if (t == 0) {
            if (tid < 64) dps64[tid] = dbias[tid];
        } else {
#pragma unroll
            for (int q = 0; q < 4; q++) {
                int a = wave * 16 + q * 4 + g16;        // [0,64)
                float sacc = 0.f;
#pragma unroll
                for (int jj = 0; jj < 4; jj++) {
                    u16x8 wv = dreg[q * 4 + jj];
                    float4 h0 = *(float4*)&hsh[jj * 128 + gl * 8];
                    float4 h1 = *(float4*)&hsh[jj * 128 + gl * 8 + 4];
                    sacc += b2f(wv[0]) * h0.x + b2f(wv[1]) * h0.y
                          + b2f(wv[2]) * h0.z + b2f(wv[3]) * h0.w
                          + b2f(wv[4]) * h1.x + b2f(wv[5]) * h1.y
                          + b2f(wv[6]) * h1.z + b2f(wv[7]) * h1.w;
                }
                sacc += __shfl_xor(sacc, 1, 64); sacc += __shfl_xor(sacc, 2, 64);
                sacc += __shfl_xor(sacc, 4, 64); sacc += __shfl_xor(sacc, 8, 64);
                if (gl == 0) dps64[a] = sacc + dbias[a];
            }
        }
        __syncthreads();

        // ---- partial energies over own 64 a's (LDS) -> tagged publish
        if (tid < 196) {
            float e = 0.f;
#pragma unroll 8
            for (int a = 0; a < 64; a++)
                e += fmaxf(b2f(ePs[a][tid]) + dps64[a], 0.f) * fws[s * 64 + a];
            u64_t w = ((u64_t)(unsigned)(t + 1) << 32) | (u64_t)f2u(e);
            __hip_atomic_store(&epq[s * 200 + tid], w,
                               __ATOMIC_RELAXED, __HIP_MEMORY_SCOPE_AGENT);
        }

        // ---- Whh^T.h slice from L2 (latency-tolerant, overlaps the e-wait)
        {
            float wa[8] = {0.f,0.f,0.f,0.f,0.f,0.f,0.f,0.f};
            const ushort_t* wp = WhhT + (size_t)(kg * 64) * 2048 + s * 256 + cg * 8;
#pragma unroll 8
            for (int kk = 0; kk < 64; kk++) {
                u16x8 wv = *(const u16x8*)&wp[(size_t)kk * 2048];
                float hv = hsh[kg * 64 + kk];
#pragma unroll
                for (int q = 0; q < 8; q++) wa[q] += b2f(wv[q]) * hv;
            }
#pragma unroll
            for (int q = 0; q < 8; q++) sred[kg][cg][q] = wa[q];
        }
        __syncthreads();
        float g = gx;
#pragma unroll
        for (int k2 = 0; k2 < 8; k2++) g += sred[k2][tid >> 3][tid & 7];

        // ---- gather 8 tagged eparts (poll all outstanding in parallel)
        if (tid < 196) {
            const unsigned tag = (unsigned)(t + 1);
            u64_t wv[8];
            unsigned ok = 0;
            while (ok != 0xffu) {
#pragma unroll
                for (int s2 = 0; s2 < 8; s2++)
                    if (!(ok & (1u << s2)))
                        wv[s2] = __hip_atomic_load(&epq[s2 * 200 + tid],
                                     __ATOMIC_RELAXED, __HIP_MEMORY_SCOPE_AGENT);
#pragma unroll
                for (int s2 = 0; s2 < 8; s2++)
                    if (!(ok & (1u << s2)) && ((unsigned)(wv[s2] >> 32) == tag))
                        ok |= 1u << s2;
                if (ok != 0xffu) __builtin_amdgcn_s_sleep(1);
            }
            float e = fb0;
#pragma unroll
            for (int s2 = 0; s2 < 8; s2++) e += u2f((unsigned)wv[s2]);
            es[tid] = e;
        }
        __syncthreads();
        if (tid < 64) {
            float v[4]; int pv[4]; int n = 0;
            for (int q = 0; q < 4; q++) {
                int p = tid + 64 * q;
                if (p < P_) { pv[n] = p; v[n] = es[p]; n++; }
            }
            float m = -1e30f;
            for (int q = 0; q < n; q++) m = fmaxf(m, v[q]);
#pragma unroll
            for (int off = 32; off > 0; off >>= 1) m = fmaxf(m, __shfl_xor(m, off, 64));
            float ssum = 0.f;
            for (int q = 0; q < n; q++) { v[q] = expf(v[q] - m); ssum += v[q]; }
#pragma unroll
            for (int off = 32; off > 0; off >>= 1) ssum += __shfl_xor(ssum, off, 64);
            float rinv = 1.f / ssum;
            for (int q = 0; q < n; q++) al[pv[q]] = v[q] * rinv;
        }
        __syncthreads();

        // ---- alpha.G slice (from LDS)
        {
            int p0 = (kg < 4) ? kg * 25 : 100 + (kg - 4) * 24;
            int np = (kg < 4) ? 25 : 24;
            float pa[8] = {0.f,0.f,0.f,0.f,0.f,0.f,0.f,0.f};
#pragma unroll 4
            for (int i = 0; i < np; i++) {
                int p = p0 + i;
                float av = al[p];
                u16x8 gv = *(const u16x8*)&Gs[p][cg * 8];
#pragma unroll
                for (int q = 0; q < 8; q++) pa[q] += b2f(gv[q]) * av;
            }
#pragma unroll
            for (int q = 0; q < 8; q++) sred[kg][cg][q] = pa[q];
        }
        __syncthreads();
#pragma unroll
        for (int k2 = 0; k2 < 8; k2++) g += sred[k2][tid >> 3][tid & 7];
        gsh[tid] = g;
        __syncthreads();

        // ---- block-local pointwise LSTM; publish tagged h(t+1)
        if (tid < 64) {
            int ri = tid >> 3, e = tid & 7;
            float gi = gsh[ri * 32 + e];
            float gf = gsh[ri * 32 + 8 + e];
            float gg = gsh[ri * 32 + 16 + e];
            float go = gsh[ri * 32 + 24 + e];
            float ig = 1.f / (1.f + expf(-gi));
            float fg = 1.f / (1.f + expf(-gf));
            float g_ = tanhf(gg);
            float og = 1.f / (1.f + expf(-go));
            c_reg = fg * c_reg + ig * g_;
            float hn = og * tanhf(c_reg);
            int u = 8 * s + 64 * ri + e;
            u64_t w = ((u64_t)(unsigned)(t + 1) << 32) | (u64_t)f2u(hn);
            __hip_atomic_store(&hbq[u], w,
                               __ATOMIC_RELAXED, __HIP_MEMORY_SCOPE_AGENT);
            hseqB[(size_t)(t + 1) * 16384 + b * 512 + u] = bf_rne(hn);
        }
        __syncthreads();
    }
}

// ---------------------------------------------------------------------------
extern "C" void kernel_launch(void* const* d_in, const int* in_sizes, int n_in,
                              void* d_out, int out_size, void* d_ws, size_t ws_size,
                              hipStream_t stream)
{
    (void)in_sizes; (void)n_in; (void)out_size; (void)ws_size;
    const float* feat   = (const float*)d_in[0];
    const int*   caps   = (const int*)  d_in[1];
    const float* emb    = (const float*)d_in[2];
    const float* W_ih   = (const float*)d_in[3];
    const float* b_ih   = (const float*)d_in[4];
    const float* W_hh   = (const float*)d_in[5];
    const float* b_hh   = (const float*)d_in[6];
    const float* fc_W   = (const float*)d_in[7];
    const float* fc_b   = (const float*)d_in[8];
    const float* enc_W  = (const float*)d_in[9];
    const float* enc_b  = (const float*)d_in[10];
    const float* dec_W  = (const float*)d_in[11];
    const float* dec_b  = (const float*)d_in[12];
    const float* full_W = (const float*)d_in[13];
    const float* full_b = (const float*)d_in[14];
    float* out = (float*)d_out;

    // workspace carve (~90 MB), 128B-aligned chunks
    char* w = (char*)d_ws;
    ushort_t* featB = (ushort_t*)w;              w += 25690112;  // [6272][2048]
    ushort_t* encWB = (ushort_t*)w;              w += 2097152;   // [512][2048]
    ushort_t* fcWB  = (ushort_t*)w;              w += 10240000;  // [10000][512]
    ushort_t* decWB = (ushort_t*)w;              w += 524288;    // [512][512]
    ushort_t* WihCB = (ushort_t*)w;              w += 8388608;   // [2048][2048] (rows permuted)
    ushort_t* WihEB = (ushort_t*)w;              w += 2097152;   // [2048][512]  (rows permuted)
    ushort_t* WhhT  = (ushort_t*)w;              w += 2097152;   // [512][2048]  (cols permuted)
    ushort_t* XB    = (ushort_t*)w;              w += 655360;    // [640][512]
    ushort_t* encPT = (ushort_t*)w;              w += 6422528;   // [512][6272] a-major
    ushort_t* GB    = (ushort_t*)w;              w += 25690112;  // [6272][2048] (cols permuted)
    float*    xproj = (float*)w;                 w += 5242880;   // [640][2048]  (cols permuted)
    float*    bsum  = (float*)w;                 w += 8192;      // [2048] (permuted)
    float*    zbuf  = (float*)w;                 w += 8192;      // [2048]
    ushort_t* hseqB = (ushort_t*)w;              w += 688128;    // [21][32][512]
    u64_t*    hbufQ = (u64_t*)w;                 w += 131072;    // [32][512] tagged
    u64_t*    epartQ= (u64_t*)w;                 w += 409600;    // [32][8][200] tagged

    // zero tagged sync buffers (contiguous; ws re-poisoned each replay)
    hipMemsetAsync(hbufQ, 0, 131072 + 409600, stream);

    // one-time converts / extracts / transposes / gathers / permutes (1 node)
    cvt_all_kernel<<<13125, 256, 0, stream>>>(
        feat, enc_W, fc_W, dec_W, W_ih, W_hh, emb, caps, b_ih, b_hh,
        featB, encWB, fcWB, decWB, WihCB, WihEB, WhhT, XB, bsum, zbuf);

    // enc_proj TRANSPOSED: [512,2048]x[6272,2048]^T -> encPT[a][b*196+p] bf16
    // (row bias enc_b[a] via mode 3)
    mfma_gemm_kernel<<<dim3(4, 49), 256, 0, stream>>>(
        encWB, featB, enc_b, encPT, nullptr, 2048, 6272, 3);

    // G = feat . W_ihC^T (rows of WihCB permuted -> GB cols permuted) bf16
    // 256^2-tile kernel: 25x8 = 200 blocks, one clean block-wave on 256 CUs
    mfma_gemm256_kernel<<<dim3(25, 8), 512, 0, stream>>>(
        featB, WihCB, zbuf, GB, 6272, 2048, 2048);

    // xproj = X . W_ihE^T + bsum (cols permuted to match)
    mfma_gemm_kernel<<<dim3(5, 16), 256, 0, stream>>>(
        XB, WihEB, bsum, nullptr, xproj, 512, 2048, 2);

    // persistent 20-step recurrent loop: data-as-flag sync, zero counters
    persist_kernel<<<NBLK, 256, 0, stream>>>(
        hbufQ, hseqB, encPT, decWB, dec_b, full_W, full_b,
        GB, WhhT, xproj, epartQ);

    // batched vocab FC: [640,512]x[10000,512]^T -> out (f32, remapped rows)
    mfma_gemm_kernel<<<dim3(5, 79), 256, 0, stream>>>(
        hseqB + 16384, fcWB, fc_b, nullptr, out, 512, V_, 1);
}